// Round 9
// baseline (726.572 us; speedup 1.0000x reference)
//
#include <hip/hip_runtime.h>
#include <hip/hip_bf16.h>
#include <cstdint>
#include <cstddef>

// Problem constants
#define CNU 500000      // item id offset
#define CB  65536       // batch
#define CE  128         // embedding dim
#define CF  172         // feature dim
#define EV  64          // events per block (4 M-tiles of 16)

typedef unsigned short ushort_t;
typedef __attribute__((ext_vector_type(8))) short b8;    // 8 x bf16
typedef __attribute__((ext_vector_type(4))) short b4;    // 4 x bf16
typedef __attribute__((ext_vector_type(4))) float f4;    // MFMA accumulator
typedef __attribute__((ext_vector_type(4))) float f32x4;

#define MFMA16(a,b,c) __builtin_amdgcn_mfma_f32_16x16x32_bf16((a),(b),(c),0,0,0)

#define NTL4(p)   __builtin_nontemporal_load((const f32x4*)(p))
#define NTLI(p)   __builtin_nontemporal_load(p)
#define NTS(v, p) __builtin_nontemporal_store((v), (p))

// ---- packed weight layout in ws (ushort elements), B-fragment order:
// frag(nt,kt): lane l holds B[k=kt*32+(l>>4)*8+j][n=nt*16+(l&15)], j=0..7
#define FRAG 512
#define U_KT 18                   // 14 k-tiles wih (K pad 448) + 4 whh
#define U_NT 24
#define U_SZ (U_NT*U_KT*FRAG)
#define PU_OFF 0
#define PI_OFF U_SZ
#define PG_OFF (2*U_SZ)
#define G_SZ (8*8*FRAG)
#define PP_OFF (PG_OFF + G_SZ)
#define P_SZ (8*4*FRAG)

// XOR-swizzle on 16B granules, both write and read sides (T2 discipline).
#define SWZ(r, c) ((c) ^ (((r) & 7) << 3))
#define AFRAG(T, r, c) (*(const b8*)&(T)[(r)][SWZ((r), (c))])

__device__ __forceinline__ unsigned pk2bf(float a, float b) {
  __hip_bfloat162 h = __float22bfloat162_rn(make_float2(a, b));   // v_cvt_pk_bf16_f32
  return *reinterpret_cast<unsigned*>(&h);
}
__device__ __forceinline__ ushort_t f2bf(float f) {
  unsigned u = __float_as_uint(f);
  return (ushort_t)((u + 0x7FFFu + ((u >> 16) & 1u)) >> 16);   // RNE scalar
}
__device__ __forceinline__ float bf2f(ushort_t h) {
  return __uint_as_float(((unsigned)h) << 16);
}
__device__ __forceinline__ float sigmoid_(float x) { return 1.0f/(1.0f+__expf(-x)); }
__device__ __forceinline__ float tanh_(float x) { float e=__expf(2.0f*x); return 1.0f-2.0f/(e+1.0f); }

// On-the-fly time projection: proj_frag = old_frag * (1 + d*tw).
// Used ONLY in fused gi (32 builds/wave, 6 MFMAs each) + pred (16 builds).
__device__ __forceinline__ b8 scale8(b8 x, float d, f32x4 t0, f32x4 t1) {
  union { ushort_t u[8]; unsigned q[4]; b8 v; } in, out;
  in.v = x;
  const float tt[8] = {t0[0],t0[1],t0[2],t0[3], t1[0],t1[1],t1[2],t1[3]};
#pragma unroll
  for (int j = 0; j < 4; ++j) {
    float a = bf2f(in.u[2*j]);
    float b = bf2f(in.u[2*j+1]);
    a = fmaf(a, d*tt[2*j],   a);
    b = fmaf(b, d*tt[2*j+1], b);
    out.q[j] = pk2bf(a, b);
  }
  return out.v;
}

// ---- LDS: 73.3 KB -> 2 blocks/CU (the point of this round).
// PU/PI/QU are NOT staged (projected on the fly from OU/OI + d + tw).
// HU dedicated; HI aliases FE after B2 (FE dead post-gi).
struct __align__(16) SLds {
  ushort_t OU[EV][128];   // 16KB old_user (h_u)
  ushort_t OI[EV][128];   // 16KB old_item (h_i)
  ushort_t FE[EV][192];   // 24KB features -> HI alias after B2
  ushort_t HU[EV][128];   // 16KB h'_u
  float TW[128];
  float DU[EV], DI[EV], DQ[EV];
};

extern "C" __global__ void prep_weights(
    const float* __restrict__ u_wih, const float* __restrict__ u_whh,
    const float* __restrict__ i_wih, const float* __restrict__ i_whh,
    const float* __restrict__ gate_w, const float* __restrict__ pred_w,
    ushort_t* __restrict__ ws)
{
  const int stride = gridDim.x * blockDim.x;
  const int tid = blockIdx.x * blockDim.x + threadIdx.x;
  for (int i = tid; i < U_SZ; i += stride) {
    const int nt = i / (U_KT*FRAG);
    const int r1 = i - nt*(U_KT*FRAG);
    const int kt = r1 / FRAG;
    const int e  = r1 - kt*FRAG;
    const int l  = e >> 3, j = e & 7;
    const int n  = nt*16 + (l & 15);
    const int k  = (l >> 4)*8 + j;
    float vu, vi;
    if (kt < 14) {
      const int kk = kt*32 + k;
      vu = (kk < 428) ? u_wih[(size_t)n*428 + kk] : 0.0f;
      vi = (kk < 428) ? i_wih[(size_t)n*428 + kk] : 0.0f;
    } else {
      const int kk = (kt - 14)*32 + k;
      vu = u_whh[(size_t)n*128 + kk];
      vi = i_whh[(size_t)n*128 + kk];
    }
    ws[PU_OFF + i] = f2bf(vu);
    ws[PI_OFF + i] = f2bf(vi);
  }
  for (int i = tid; i < G_SZ; i += stride) {
    const int nt = i / (8*FRAG);
    const int r1 = i - nt*(8*FRAG);
    const int kt = r1 / FRAG;
    const int e  = r1 - kt*FRAG;
    const int l  = e >> 3, j = e & 7;
    const int n  = nt*16 + (l & 15);
    const int kk = kt*32 + (l >> 4)*8 + j;
    ws[PG_OFF + i] = f2bf(gate_w[(size_t)n*256 + kk]);
  }
  for (int i = tid; i < P_SZ; i += stride) {
    const int nt = i / (4*FRAG);
    const int r1 = i - nt*(4*FRAG);
    const int kt = r1 / FRAG;
    const int e  = r1 - kt*FRAG;
    const int l  = e >> 3, j = e & 7;
    const int n  = nt*16 + (l & 15);
    const int kk = kt*32 + (l >> 4)*8 + j;
    ws[PP_OFF + i] = f2bf(pred_w[(size_t)n*128 + kk]);
  }
}

extern "C" __global__ void __launch_bounds__(512, 4)
jodie_main(const int* __restrict__ user_ids, const int* __restrict__ item_ids,
           const float* __restrict__ timestamps, const float* __restrict__ features,
           const int* __restrict__ query_time, const float* __restrict__ memv,
           const float* __restrict__ last_time, const float* __restrict__ time_w,
           const float* __restrict__ u_bih, const float* __restrict__ u_bhh,
           const float* __restrict__ i_bih, const float* __restrict__ i_bhh,
           const float* __restrict__ gate_b, const float* __restrict__ pred_b,
           const ushort_t* __restrict__ ws, float* __restrict__ d_out)
{
  __shared__ SLds s;
  ushort_t (*HI)[128] = (ushort_t (*)[128])(&s.FE[0][0]);   // alias (dead FE)
  const int t  = threadIdx.x;
  const int e0 = blockIdx.x * EV;

  // ---- stage: OU/OI + d scalars + TW + FE (no proj tiles) ----
  if (t < 32) *(float4*)&s.TW[t*4] = *(const float4*)&time_w[t*4];
  {
    const int c8 = (t & 15) * 8;
    const float qt = (float)query_time[0];
#pragma unroll
    for (int ep = 0; ep < 2; ++ep) {
      const int e  = ep*32 + (t >> 4);
      const int ge = e0 + e;
      const int u   = NTLI(&user_ids[ge]);
      const int itn = NTLI(&item_ids[ge]) + CNU;
      const float ts = NTLI(&timestamps[ge]);
      const float lu = NTLI(&last_time[u]);
      const float li = NTLI(&last_time[itn]);
      if ((t & 15) == 0) {
        s.DU[e] = ts - lu;
        s.DI[e] = ts - li;
        s.DQ[e] = qt - lu;
      }
      const f32x4 ou0 = NTL4(&memv[(size_t)u  *CE + c8]);
      const f32x4 ou1 = NTL4(&memv[(size_t)u  *CE + c8 + 4]);
      const f32x4 oi0 = NTL4(&memv[(size_t)itn*CE + c8]);
      const f32x4 oi1 = NTL4(&memv[(size_t)itn*CE + c8 + 4]);
      union { unsigned q[4]; b8 v; } hu, hi;
      hu.q[0] = pk2bf(ou0[0], ou0[1]);  hu.q[1] = pk2bf(ou0[2], ou0[3]);
      hu.q[2] = pk2bf(ou1[0], ou1[1]);  hu.q[3] = pk2bf(ou1[2], ou1[3]);
      hi.q[0] = pk2bf(oi0[0], oi0[1]);  hi.q[1] = pk2bf(oi0[2], oi0[3]);
      hi.q[2] = pk2bf(oi1[0], oi1[1]);  hi.q[3] = pk2bf(oi1[2], oi1[3]);
      *(b8*)&s.OU[e][SWZ(e, c8)] = hu.v;
      *(b8*)&s.OI[e][SWZ(e, c8)] = hi.v;
    }
  }
  for (int i = t; i < EV*43; i += 512) {
    const int e = i / 43, q = i - e*43;
    const f32x4 fv = NTL4(&features[(size_t)(e0 + e)*CF + q*4]);
    union { unsigned q2[2]; b4 v; } fb;
    fb.q2[0] = pk2bf(fv[0], fv[1]);
    fb.q2[1] = pk2bf(fv[2], fv[3]);
    *(b4*)&s.FE[e][SWZ(e, q*4)] = fb.v;
  }
  for (int i = t; i < EV*20; i += 512) {
    const int e = i / 20, c = 172 + (i - e*20);
    s.FE[e][SWZ(e, c)] = 0;
  }
  __syncthreads();   // B1

  const int wv   = t >> 6, l = t & 63;
  const int lrow = l & 15;
  const int lk   = (l >> 4) * 8;
  const int col  = wv*16 + lrow;

  const ushort_t* Wru = ws + PU_OFF + (size_t)(wv     )*U_KT*FRAG + l*8;
  const ushort_t* Wzu = ws + PU_OFF + (size_t)(wv +  8)*U_KT*FRAG + l*8;
  const ushort_t* Wnu = ws + PU_OFF + (size_t)(wv + 16)*U_KT*FRAG + l*8;
  const ushort_t* Wri = ws + PI_OFF + (size_t)(wv     )*U_KT*FRAG + l*8;
  const ushort_t* Wzi = ws + PI_OFF + (size_t)(wv +  8)*U_KT*FRAG + l*8;
  const ushort_t* Wni = ws + PI_OFF + (size_t)(wv + 16)*U_KT*FRAG + l*8;
  const ushort_t* WP  = ws + PP_OFF + (size_t)wv*4*FRAG + l*8;
  const ushort_t* WG  = ws + PG_OFF + (size_t)wv*8*FRAG + l*8;

  // ---- pred: qu = OU*(1+dq*tw) built on the fly (16 scale8/wave) ----
  {
    const float bp = pred_b[col];
    f4 ap[4];
#pragma unroll
    for (int m = 0; m < 4; ++m) ap[m] = (f4){bp,bp,bp,bp};
#pragma unroll
    for (int kt = 0; kt < 4; ++kt) {
      b8 fp = *(const b8*)(WP + (size_t)kt*FRAG);
      const f32x4 t0 = *(const f32x4*)&s.TW[32*kt + lk];
      const f32x4 t1 = *(const f32x4*)&s.TW[32*kt + lk + 4];
#pragma unroll
      for (int m = 0; m < 4; ++m) {
        b8 a = scale8(AFRAG(s.OU, m*16 + lrow, 32*kt + lk), s.DQ[m*16 + lrow], t0, t1);
        ap[m] = MFMA16(a, fp, ap[m]);
      }
    }
#pragma unroll
    for (int m = 0; m < 4; ++m)
#pragma unroll
      for (int r4 = 0; r4 < 4; ++r4) {
        const int row = m*16 + (l >> 4)*4 + r4;
        NTS(ap[m][r4], &d_out[(size_t)(e0 + row)*CE + col]);
      }
  }

  // ---- biases ----
  const float bru = u_bih[col]     + u_bhh[col];
  const float bzu = u_bih[col+128] + u_bhh[col+128];
  const float bnu = u_bih[col+256];
  const float bhu = u_bhh[col+256];
  const float bri = i_bih[col]     + i_bhh[col];
  const float bzi = i_bih[col+128] + i_bhh[col+128];
  const float bni = i_bih[col+256];
  const float bhi = i_bhh[col+256];

  f4 aru[4], azu[4], anu[4], ari[4], azi[4], ani[4];
#pragma unroll
  for (int m = 0; m < 4; ++m) {
    aru[m] = (f4){bru,bru,bru,bru};  azu[m] = (f4){bzu,bzu,bzu,bzu};
    anu[m] = (f4){bnu,bnu,bnu,bnu};  ari[m] = (f4){bri,bri,bri,bri};
    azi[m] = (f4){bzi,bzi,bzi,bzi};  ani[m] = (f4){bni,bni,bni,bni};
  }

  // ---- FUSED gi: on-the-fly projected A-fragment feeds 6 MFMAs ----
#define GI_STEPP(TILE, DARR, kk, ktu, kti)                                    \
  {                                                                           \
    const f32x4 t0 = *(const f32x4*)&s.TW[32*(kk) + lk];                      \
    const f32x4 t1 = *(const f32x4*)&s.TW[32*(kk) + lk + 4];                  \
    b8 a_[4];                                                                 \
    _Pragma("unroll")                                                         \
    for (int m = 0; m < 4; ++m)                                               \
      a_[m] = scale8(AFRAG(TILE, m*16 + lrow, 32*(kk) + lk),                  \
                     (DARR)[m*16 + lrow], t0, t1);                            \
    b8 fru = *(const b8*)(Wru + (size_t)(ktu)*FRAG);                          \
    b8 fzu = *(const b8*)(Wzu + (size_t)(ktu)*FRAG);                          \
    b8 fnu = *(const b8*)(Wnu + (size_t)(ktu)*FRAG);                          \
    b8 fri = *(const b8*)(Wri + (size_t)(kti)*FRAG);                          \
    b8 fzi = *(const b8*)(Wzi + (size_t)(kti)*FRAG);                          \
    b8 fni = *(const b8*)(Wni + (size_t)(kti)*FRAG);                          \
    _Pragma("unroll")                                                         \
    for (int m = 0; m < 4; ++m) {                                             \
      aru[m] = MFMA16(a_[m], fru, aru[m]);                                    \
      azu[m] = MFMA16(a_[m], fzu, azu[m]);                                    \
      anu[m] = MFMA16(a_[m], fnu, anu[m]);                                    \
      ari[m] = MFMA16(a_[m], fri, ari[m]);                                    \
      azi[m] = MFMA16(a_[m], fzi, azi[m]);                                    \
      ani[m] = MFMA16(a_[m], fni, ani[m]);                                    \
    }                                                                         \
  }
#define GI_STEPF(kk, ktu, kti)                                                \
  {                                                                           \
    b8 a_[4];                                                                 \
    _Pragma("unroll")                                                         \
    for (int m = 0; m < 4; ++m)                                               \
      a_[m] = AFRAG(s.FE, m*16 + lrow, 32*(kk) + lk);                         \
    b8 fru = *(const b8*)(Wru + (size_t)(ktu)*FRAG);                          \
    b8 fzu = *(const b8*)(Wzu + (size_t)(ktu)*FRAG);                          \
    b8 fnu = *(const b8*)(Wnu + (size_t)(ktu)*FRAG);                          \
    b8 fri = *(const b8*)(Wri + (size_t)(kti)*FRAG);                          \
    b8 fzi = *(const b8*)(Wzi + (size_t)(kti)*FRAG);                          \
    b8 fni = *(const b8*)(Wni + (size_t)(kti)*FRAG);                          \
    _Pragma("unroll")                                                         \
    for (int m = 0; m < 4; ++m) {                                             \
      aru[m] = MFMA16(a_[m], fru, aru[m]);                                    \
      azu[m] = MFMA16(a_[m], fzu, azu[m]);                                    \
      anu[m] = MFMA16(a_[m], fnu, anu[m]);                                    \
      ari[m] = MFMA16(a_[m], fri, ari[m]);                                    \
      azi[m] = MFMA16(a_[m], fzi, azi[m]);                                    \
      ani[m] = MFMA16(a_[m], fni, ani[m]);                                    \
    }                                                                         \
  }

#pragma unroll
  for (int pf = 0; pf < 4; ++pf) GI_STEPP(s.OU, s.DU, pf, pf, pf + 4)   // proj_user
#pragma unroll
  for (int pf = 0; pf < 4; ++pf) GI_STEPP(s.OI, s.DI, pf, pf + 4, pf)   // proj_item
#pragma unroll
  for (int pf = 0; pf < 6; ++pf) GI_STEPF(pf, pf + 8, pf + 8)           // features
#undef GI_STEPP
#undef GI_STEPF

  // ---- user gh (K=128) + ew -> h'_u into dedicated HU ----
  {
    f4 ah[4];
#pragma unroll
    for (int m = 0; m < 4; ++m) ah[m] = (f4){bhu,bhu,bhu,bhu};
#pragma unroll
    for (int kt = 0; kt < 4; ++kt) {
      b8 fr = *(const b8*)(Wru + (size_t)(14+kt)*FRAG);
      b8 fz = *(const b8*)(Wzu + (size_t)(14+kt)*FRAG);
      b8 fn = *(const b8*)(Wnu + (size_t)(14+kt)*FRAG);
#pragma unroll
      for (int m = 0; m < 4; ++m) {
        b8 h = AFRAG(s.OU, m*16 + lrow, 32*kt + lk);
        aru[m] = MFMA16(h, fr, aru[m]);
        azu[m] = MFMA16(h, fz, azu[m]);
        ah[m]  = MFMA16(h, fn, ah[m]);
      }
    }
#pragma unroll
    for (int m = 0; m < 4; ++m)
#pragma unroll
      for (int r4 = 0; r4 < 4; ++r4) {
        const int row = m*16 + (l >> 4)*4 + r4;
        const float rr = sigmoid_(aru[m][r4]);
        const float zz = sigmoid_(azu[m][r4]);
        const float nn = tanh_(anu[m][r4] + rr*ah[m][r4]);
        const float h  = bf2f(s.OU[row][SWZ(row, col)]);
        s.HU[row][SWZ(row, col)] = f2bf((1.0f - zz)*nn + zz*h);   // HU dedicated
      }
  }

  // ---- item gh + ew -> registers (HI write deferred past B2) ----
  float hpvi[16];
  {
    f4 ah[4];
#pragma unroll
    for (int m = 0; m < 4; ++m) ah[m] = (f4){bhi,bhi,bhi,bhi};
#pragma unroll
    for (int kt = 0; kt < 4; ++kt) {
      b8 fr = *(const b8*)(Wri + (size_t)(14+kt)*FRAG);
      b8 fz = *(const b8*)(Wzi + (size_t)(14+kt)*FRAG);
      b8 fn = *(const b8*)(Wni + (size_t)(14+kt)*FRAG);
#pragma unroll
      for (int m = 0; m < 4; ++m) {
        b8 h = AFRAG(s.OI, m*16 + lrow, 32*kt + lk);
        ari[m] = MFMA16(h, fr, ari[m]);
        azi[m] = MFMA16(h, fz, azi[m]);
        ah[m]  = MFMA16(h, fn, ah[m]);
      }
    }
#pragma unroll
    for (int m = 0; m < 4; ++m)
#pragma unroll
      for (int r4 = 0; r4 < 4; ++r4) {
        const int row = m*16 + (l >> 4)*4 + r4;
        const float rr = sigmoid_(ari[m][r4]);
        const float zz = sigmoid_(azi[m][r4]);
        const float nn = tanh_(ani[m][r4] + rr*ah[m][r4]);
        const float h  = bf2f(s.OI[row][SWZ(row, col)]);
        hpvi[m*4 + r4] = (1.0f - zz)*nn + zz*h;
      }
  }
  __syncthreads();   // B2: all waves done reading FE -> HI alias safe

#pragma unroll
  for (int m = 0; m < 4; ++m)
#pragma unroll
    for (int r4 = 0; r4 < 4; ++r4) {
      const int row = m*16 + (l >> 4)*4 + r4;
      HI[row][SWZ(row, col)] = f2bf(hpvi[m*4 + r4]);
    }
  __syncthreads();   // B3: HU + HI visible to all waves

  // ---- memory gates: shared gate_w fragments, user+item A streams ----
  {
    const float gb = gate_b[col];
    f4 agu[4], agi[4];
#pragma unroll
    for (int m = 0; m < 4; ++m) { agu[m] = (f4){gb,gb,gb,gb}; agi[m] = agu[m]; }
#pragma unroll
    for (int kt = 0; kt < 8; ++kt) {
      b8 fg = *(const b8*)(WG + (size_t)kt*FRAG);
#pragma unroll
      for (int m = 0; m < 4; ++m) {
        b8 au = (kt < 4) ? AFRAG(s.OU, m*16 + lrow, 32*kt + lk)
                         : AFRAG(s.HU, m*16 + lrow, 32*(kt-4) + lk);
        b8 ai = (kt < 4) ? AFRAG(s.OI, m*16 + lrow, 32*kt + lk)
                         : AFRAG(HI,   m*16 + lrow, 32*(kt-4) + lk);
        agu[m] = MFMA16(au, fg, agu[m]);
        agi[m] = MFMA16(ai, fg, agi[m]);
      }
    }
    float* __restrict__ outu = d_out + (size_t)CB*CE;
    float* __restrict__ outi = d_out + (size_t)2*CB*CE;
#pragma unroll
    for (int m = 0; m < 4; ++m)
#pragma unroll
      for (int r4 = 0; r4 < 4; ++r4) {
        const int row = m*16 + (l >> 4)*4 + r4;
        const float gu = sigmoid_(agu[m][r4]);
        const float gi = sigmoid_(agi[m][r4]);
        const float hu  = bf2f(s.OU[row][SWZ(row, col)]);
        const float hpu = bf2f(s.HU[row][SWZ(row, col)]);
        const float hi  = bf2f(s.OI[row][SWZ(row, col)]);
        const float hpi = bf2f(HI[row][SWZ(row, col)]);
        NTS(gu*hpu + (1.0f - gu)*hu, &outu[(size_t)(e0 + row)*CE + col]);
        NTS(gi*hpi + (1.0f - gi)*hi, &outi[(size_t)(e0 + row)*CE + col]);
      }
  }
}

extern "C" void kernel_launch(void* const* d_in, const int* in_sizes, int n_in,
                              void* d_out, int out_size, void* d_ws, size_t ws_size,
                              hipStream_t stream) {
  const int*   user_ids   = (const int*)d_in[0];
  const int*   item_ids   = (const int*)d_in[1];
  const float* timestamps = (const float*)d_in[2];
  const float* features   = (const float*)d_in[3];
  const int*   query_time = (const int*)d_in[4];
  const float* memv       = (const float*)d_in[5];
  const float* last_time  = (const float*)d_in[6];
  const float* time_w     = (const float*)d_in[7];
  const float* u_wih = (const float*)d_in[8];
  const float* u_whh = (const float*)d_in[9];
  const float* u_bih = (const float*)d_in[10];
  const float* u_bhh = (const float*)d_in[11];
  const float* i_wih = (const float*)d_in[12];
  const float* i_whh = (const float*)d_in[13];
  const float* i_bih = (const float*)d_in[14];
  const float* i_bhh = (const float*)d_in[15];
  const float* gate_w = (const float*)d_in[16];
  const float* gate_b = (const float*)d_in[17];
  const float* pred_w = (const float*)d_in[18];
  const float* pred_b = (const float*)d_in[19];
  ushort_t* ws = (ushort_t*)d_ws;
  float* out = (float*)d_out;

  prep_weights<<<dim3(256), dim3(256), 0, stream>>>(u_wih, u_whh, i_wih, i_whh,
                                                    gate_w, pred_w, ws);
  jodie_main<<<dim3(CB/EV), dim3(512), 0, stream>>>(user_ids, item_ids, timestamps,
                                                    features, query_time, memv,
                                                    last_time, time_w,
                                                    u_bih, u_bhh, i_bih, i_bhh,
                                                    gate_b, pred_b, ws, out);
}

// Round 10
// 598.277 us; speedup vs baseline: 1.2144x; 1.2144x over previous
//
#include <hip/hip_runtime.h>
#include <hip/hip_bf16.h>
#include <cstdint>
#include <cstddef>

// Problem constants
#define CNU 500000      // item id offset
#define CB  65536       // batch
#define CE  128         // embedding dim
#define CF  172         // feature dim
#define EV  128         // events per block (two 64-event halves, split across wave groups)

typedef unsigned short ushort_t;
typedef __attribute__((ext_vector_type(8))) short b8;    // 8 x bf16
typedef __attribute__((ext_vector_type(4))) float f4;    // MFMA accumulator
typedef __attribute__((ext_vector_type(4))) float f32x4;

#define MFMA16(a,b,c) __builtin_amdgcn_mfma_f32_16x16x32_bf16((a),(b),(c),0,0,0)

#define NTL4(p)   __builtin_nontemporal_load((const f32x4*)(p))
#define NTLI(p)   __builtin_nontemporal_load(p)
#define NTS(v, p) __builtin_nontemporal_store((v), (p))

// ---- packed weight layout in ws (ushort elements), B-fragment order:
// frag(nt,kt): lane l holds B[k=kt*32+(l>>4)*8+j][n=nt*16+(l&15)], j=0..7
#define FRAG 512
#define U_KT 18                   // 14 k-tiles wih (K pad 448) + 4 whh
#define U_NT 24
#define U_SZ (U_NT*U_KT*FRAG)
#define PU_OFF 0
#define PI_OFF U_SZ
#define PG_OFF (2*U_SZ)
#define G_SZ (8*8*FRAG)
#define PP_OFF (PG_OFF + G_SZ)
#define P_SZ (8*4*FRAG)

// XOR-swizzle on 16B granules, both write and read sides (T2 discipline).
#define SWZ(r, c) ((c) ^ (((r) & 7) << 3))
#define AFRAG(T, r, c) (*(const b8*)&(T)[(r)][SWZ((r), (c))])

__device__ __forceinline__ unsigned pk2bf(float a, float b) {
  __hip_bfloat162 h = __float22bfloat162_rn(make_float2(a, b));   // v_cvt_pk_bf16_f32
  return *reinterpret_cast<unsigned*>(&h);
}
__device__ __forceinline__ ushort_t f2bf(float f) {
  unsigned u = __float_as_uint(f);
  return (ushort_t)((u + 0x7FFFu + ((u >> 16) & 1u)) >> 16);   // RNE scalar
}
__device__ __forceinline__ float bf2f(ushort_t h) {
  return __uint_as_float(((unsigned)h) << 16);
}
__device__ __forceinline__ float sigmoid_(float x) { return 1.0f/(1.0f+__expf(-x)); }
__device__ __forceinline__ float tanh_(float x) { float e=__expf(2.0f*x); return 1.0f-2.0f/(e+1.0f); }

// On-the-fly projection (pred only: 16 builds/wave, transient temps).
__device__ __forceinline__ b8 scale8(b8 x, float d, f32x4 t0, f32x4 t1) {
  union { ushort_t u[8]; unsigned q[4]; b8 v; } in, out;
  in.v = x;
  const float tt[8] = {t0[0],t0[1],t0[2],t0[3], t1[0],t1[1],t1[2],t1[3]};
#pragma unroll
  for (int j = 0; j < 4; ++j) {
    float a = bf2f(in.u[2*j]);
    float b = bf2f(in.u[2*j+1]);
    a = fmaf(a, d*tt[2*j],   a);
    b = fmaf(b, d*tt[2*j+1], b);
    out.q[j] = pk2bf(a, b);
  }
  return out.v;
}

// Feature A-fragment straight from global fp32 (read-once; no LDS staging).
// kf==5 uses predicated scalar loads: cols >=172 are zero (weights there are
// zero-padded anyway) and must not read out of bounds.
__device__ __forceinline__ b8 fe_frag(const float* __restrict__ features,
                                      int grow, int kf, int lk) {
  union { unsigned q[4]; b8 v; } r;
  if (kf < 5) {
    const float* fp = features + (size_t)grow*CF + 32*kf + lk;
    const f32x4 x0 = NTL4(fp);
    const f32x4 x1 = NTL4(fp + 4);
    r.q[0] = pk2bf(x0[0], x0[1]);  r.q[1] = pk2bf(x0[2], x0[3]);
    r.q[2] = pk2bf(x1[0], x1[1]);  r.q[3] = pk2bf(x1[2], x1[3]);
  } else {
    float v[8];
#pragma unroll
    for (int j = 0; j < 8; ++j) {
      const int c = 160 + lk + j;
      v[j] = (c < CF) ? features[(size_t)grow*CF + c] : 0.0f;
    }
    r.q[0] = pk2bf(v[0], v[1]);  r.q[1] = pk2bf(v[2], v[3]);
    r.q[2] = pk2bf(v[4], v[5]);  r.q[3] = pk2bf(v[6], v[7]);
  }
  return r.v;
}

// ---- LDS: 132 KB, 1 block/CU, 16 waves (4/SIMD).
// PU/PI staged WITH projection (like R4); h' overwrites them in place after B2.
// Features are NOT staged (global-direct). QU not staged (pred on the fly).
struct __align__(16) SLds {
  ushort_t PU[EV][128];   // proj_user -> h'_u after B2
  ushort_t PI[EV][128];   // proj_item -> h'_i after B2
  ushort_t OU[EV][128];   // old_user (h_u)
  ushort_t OI[EV][128];   // old_item (h_i)
  float TW[128];
  float DQ[EV];
};

extern "C" __global__ void prep_weights(
    const float* __restrict__ u_wih, const float* __restrict__ u_whh,
    const float* __restrict__ i_wih, const float* __restrict__ i_whh,
    const float* __restrict__ gate_w, const float* __restrict__ pred_w,
    ushort_t* __restrict__ ws)
{
  const int stride = gridDim.x * blockDim.x;
  const int tid = blockIdx.x * blockDim.x + threadIdx.x;
  for (int i = tid; i < U_SZ; i += stride) {
    const int nt = i / (U_KT*FRAG);
    const int r1 = i - nt*(U_KT*FRAG);
    const int kt = r1 / FRAG;
    const int e  = r1 - kt*FRAG;
    const int l  = e >> 3, j = e & 7;
    const int n  = nt*16 + (l & 15);
    const int k  = (l >> 4)*8 + j;
    float vu, vi;
    if (kt < 14) {
      const int kk = kt*32 + k;
      vu = (kk < 428) ? u_wih[(size_t)n*428 + kk] : 0.0f;
      vi = (kk < 428) ? i_wih[(size_t)n*428 + kk] : 0.0f;
    } else {
      const int kk = (kt - 14)*32 + k;
      vu = u_whh[(size_t)n*128 + kk];
      vi = i_whh[(size_t)n*128 + kk];
    }
    ws[PU_OFF + i] = f2bf(vu);
    ws[PI_OFF + i] = f2bf(vi);
  }
  for (int i = tid; i < G_SZ; i += stride) {
    const int nt = i / (8*FRAG);
    const int r1 = i - nt*(8*FRAG);
    const int kt = r1 / FRAG;
    const int e  = r1 - kt*FRAG;
    const int l  = e >> 3, j = e & 7;
    const int n  = nt*16 + (l & 15);
    const int kk = kt*32 + (l >> 4)*8 + j;
    ws[PG_OFF + i] = f2bf(gate_w[(size_t)n*256 + kk]);
  }
  for (int i = tid; i < P_SZ; i += stride) {
    const int nt = i / (4*FRAG);
    const int r1 = i - nt*(4*FRAG);
    const int kt = r1 / FRAG;
    const int e  = r1 - kt*FRAG;
    const int l  = e >> 3, j = e & 7;
    const int n  = nt*16 + (l & 15);
    const int kk = kt*32 + (l >> 4)*8 + j;
    ws[PP_OFF + i] = f2bf(pred_w[(size_t)n*128 + kk]);
  }
}

// 16 waves: wave w handles events [mbase, mbase+64) where mbase=(w>>3)*64,
// gate columns {wv, wv+8, wv+16} where wv=w&7. Per-wave program == R4's
// proven 128-VGPR structure; each weight fragment demanded once per 128 events.
extern "C" __global__ void __launch_bounds__(1024)
jodie_main(const int* __restrict__ user_ids, const int* __restrict__ item_ids,
           const float* __restrict__ timestamps, const float* __restrict__ features,
           const int* __restrict__ query_time, const float* __restrict__ memv,
           const float* __restrict__ last_time, const float* __restrict__ time_w,
           const float* __restrict__ u_bih, const float* __restrict__ u_bhh,
           const float* __restrict__ i_bih, const float* __restrict__ i_bhh,
           const float* __restrict__ gate_b, const float* __restrict__ pred_b,
           const ushort_t* __restrict__ ws, float* __restrict__ d_out)
{
  __shared__ SLds s;
  const int t  = threadIdx.x;
  const int e0 = blockIdx.x * EV;

  // ---- stage: PU/PI (projected) + OU/OI + TW + DQ; 16 thr/event, 2 passes ----
  if (t < 32) *(float4*)&s.TW[t*4] = *(const float4*)&time_w[t*4];
  {
    const int c8 = (t & 15) * 8;
    const float qt = (float)query_time[0];
    const float4 tw0 = *(const float4*)&time_w[c8];
    const float4 tw1 = *(const float4*)&time_w[c8 + 4];
    const float twv[8] = {tw0.x,tw0.y,tw0.z,tw0.w, tw1.x,tw1.y,tw1.z,tw1.w};
#pragma unroll
    for (int ep = 0; ep < 2; ++ep) {
      const int e  = ep*64 + (t >> 4);
      const int ge = e0 + e;
      const int u   = NTLI(&user_ids[ge]);
      const int itn = NTLI(&item_ids[ge]) + CNU;
      const float ts = NTLI(&timestamps[ge]);
      const float lu = NTLI(&last_time[u]);
      const float li = NTLI(&last_time[itn]);
      const float du = ts - lu, di = ts - li;
      if ((t & 15) == 0) s.DQ[e] = qt - lu;

      const f32x4 ou0 = NTL4(&memv[(size_t)u  *CE + c8]);
      const f32x4 ou1 = NTL4(&memv[(size_t)u  *CE + c8 + 4]);
      const f32x4 oi0 = NTL4(&memv[(size_t)itn*CE + c8]);
      const f32x4 oi1 = NTL4(&memv[(size_t)itn*CE + c8 + 4]);
      const float ouv[8] = {ou0[0],ou0[1],ou0[2],ou0[3], ou1[0],ou1[1],ou1[2],ou1[3]};
      const float oiv[8] = {oi0[0],oi0[1],oi0[2],oi0[3], oi1[0],oi1[1],oi1[2],oi1[3]};

      union U8 { unsigned q[4]; b8 v; };
      U8 xu, xi, hu, hi;
#pragma unroll
      for (int j = 0; j < 8; j += 2) {
        xu.q[j>>1] = pk2bf(ouv[j]*(1.0f + du*twv[j]), ouv[j+1]*(1.0f + du*twv[j+1]));
        xi.q[j>>1] = pk2bf(oiv[j]*(1.0f + di*twv[j]), oiv[j+1]*(1.0f + di*twv[j+1]));
        hu.q[j>>1] = pk2bf(ouv[j], ouv[j+1]);
        hi.q[j>>1] = pk2bf(oiv[j], oiv[j+1]);
      }
      *(b8*)&s.PU[e][SWZ(e, c8)] = xu.v;
      *(b8*)&s.PI[e][SWZ(e, c8)] = xi.v;
      *(b8*)&s.OU[e][SWZ(e, c8)] = hu.v;
      *(b8*)&s.OI[e][SWZ(e, c8)] = hi.v;
    }
  }
  __syncthreads();   // B1

  const int w     = t >> 6;          // 0..15
  const int wv    = w & 7;
  const int mbase = (w >> 3) * 64;   // event-half owned by this wave
  const int l     = t & 63;
  const int lrow  = l & 15;
  const int lk    = (l >> 4) * 8;
  const int col   = wv*16 + lrow;

  const ushort_t* Wru = ws + PU_OFF + (size_t)(wv     )*U_KT*FRAG + l*8;
  const ushort_t* Wzu = ws + PU_OFF + (size_t)(wv +  8)*U_KT*FRAG + l*8;
  const ushort_t* Wnu = ws + PU_OFF + (size_t)(wv + 16)*U_KT*FRAG + l*8;
  const ushort_t* Wri = ws + PI_OFF + (size_t)(wv     )*U_KT*FRAG + l*8;
  const ushort_t* Wzi = ws + PI_OFF + (size_t)(wv +  8)*U_KT*FRAG + l*8;
  const ushort_t* Wni = ws + PI_OFF + (size_t)(wv + 16)*U_KT*FRAG + l*8;
  const ushort_t* WP  = ws + PP_OFF + (size_t)wv*4*FRAG + l*8;
  const ushort_t* WG  = ws + PG_OFF + (size_t)wv*8*FRAG + l*8;

  // ---- pred: qu built on the fly from OU (16 scale8/wave) ----
  {
    const float bp = pred_b[col];
    f4 ap[4];
#pragma unroll
    for (int m = 0; m < 4; ++m) ap[m] = (f4){bp,bp,bp,bp};
#pragma unroll
    for (int kt = 0; kt < 4; ++kt) {
      b8 fp = *(const b8*)(WP + (size_t)kt*FRAG);
      const f32x4 t0 = *(const f32x4*)&s.TW[32*kt + lk];
      const f32x4 t1 = *(const f32x4*)&s.TW[32*kt + lk + 4];
#pragma unroll
      for (int m = 0; m < 4; ++m) {
        const int row = mbase + m*16 + lrow;
        b8 a = scale8(AFRAG(s.OU, row, 32*kt + lk), s.DQ[row], t0, t1);
        ap[m] = MFMA16(a, fp, ap[m]);
      }
    }
#pragma unroll
    for (int m = 0; m < 4; ++m)
#pragma unroll
      for (int r4 = 0; r4 < 4; ++r4) {
        const int row = mbase + m*16 + (l >> 4)*4 + r4;
        NTS(ap[m][r4], &d_out[(size_t)(e0 + row)*CE + col]);
      }
  }

  // ---- biases ----
  const float bru = u_bih[col]     + u_bhh[col];
  const float bzu = u_bih[col+128] + u_bhh[col+128];
  const float bnu = u_bih[col+256];
  const float bhu = u_bhh[col+256];
  const float bri = i_bih[col]     + i_bhh[col];
  const float bzi = i_bih[col+128] + i_bhh[col+128];
  const float bni = i_bih[col+256];
  const float bhi = i_bhh[col+256];

  f4 aru[4], azu[4], anu[4], ari[4], azi[4], ani[4];
#pragma unroll
  for (int m = 0; m < 4; ++m) {
    aru[m] = (f4){bru,bru,bru,bru};  azu[m] = (f4){bzu,bzu,bzu,bzu};
    anu[m] = (f4){bnu,bnu,bnu,bnu};  ari[m] = (f4){bri,bri,bri,bri};
    azi[m] = (f4){bzi,bzi,bzi,bzi};  ani[m] = (f4){bni,bni,bni,bni};
  }

  // ---- FUSED gi: A-fragment (this wave's event-half) feeds 6 MFMAs ----
#define GI_MM(ktu, kti)                                                       \
    b8 fru = *(const b8*)(Wru + (size_t)(ktu)*FRAG);                          \
    b8 fzu = *(const b8*)(Wzu + (size_t)(ktu)*FRAG);                          \
    b8 fnu = *(const b8*)(Wnu + (size_t)(ktu)*FRAG);                          \
    b8 fri = *(const b8*)(Wri + (size_t)(kti)*FRAG);                          \
    b8 fzi = *(const b8*)(Wzi + (size_t)(kti)*FRAG);                          \
    b8 fni = *(const b8*)(Wni + (size_t)(kti)*FRAG);                          \
    _Pragma("unroll")                                                         \
    for (int m = 0; m < 4; ++m) {                                             \
      aru[m] = MFMA16(a_[m], fru, aru[m]);                                    \
      azu[m] = MFMA16(a_[m], fzu, azu[m]);                                    \
      anu[m] = MFMA16(a_[m], fnu, anu[m]);                                    \
      ari[m] = MFMA16(a_[m], fri, ari[m]);                                    \
      azi[m] = MFMA16(a_[m], fzi, azi[m]);                                    \
      ani[m] = MFMA16(a_[m], fni, ani[m]);                                    \
    }

#pragma unroll
  for (int pf = 0; pf < 4; ++pf) {       // proj_user: user kt=pf, item kt=pf+4
    b8 a_[4];
#pragma unroll
    for (int m = 0; m < 4; ++m) a_[m] = AFRAG(s.PU, mbase + m*16 + lrow, 32*pf + lk);
    GI_MM(pf, pf + 4)
  }
#pragma unroll
  for (int pf = 0; pf < 4; ++pf) {       // proj_item: user kt=pf+4, item kt=pf
    b8 a_[4];
#pragma unroll
    for (int m = 0; m < 4; ++m) a_[m] = AFRAG(s.PI, mbase + m*16 + lrow, 32*pf + lk);
    GI_MM(pf + 4, pf)
  }
#pragma unroll
  for (int kf = 0; kf < 6; ++kf) {       // features (global-direct), kt=kf+8
    b8 a_[4];
#pragma unroll
    for (int m = 0; m < 4; ++m)
      a_[m] = fe_frag(features, e0 + mbase + m*16 + lrow, kf, lk);
    GI_MM(kf + 8, kf + 8)
  }
#undef GI_MM

  // ---- user gh (K=128) ----
  f4 ahu[4];
#pragma unroll
  for (int m = 0; m < 4; ++m) ahu[m] = (f4){bhu,bhu,bhu,bhu};
#pragma unroll
  for (int kt = 0; kt < 4; ++kt) {
    b8 fr = *(const b8*)(Wru + (size_t)(14+kt)*FRAG);
    b8 fz = *(const b8*)(Wzu + (size_t)(14+kt)*FRAG);
    b8 fn = *(const b8*)(Wnu + (size_t)(14+kt)*FRAG);
#pragma unroll
    for (int m = 0; m < 4; ++m) {
      b8 h = AFRAG(s.OU, mbase + m*16 + lrow, 32*kt + lk);
      aru[m] = MFMA16(h, fr, aru[m]);
      azu[m] = MFMA16(h, fz, azu[m]);
      ahu[m] = MFMA16(h, fn, ahu[m]);
    }
  }
  __syncthreads();   // B2: all waves done reading PU/PI (gi) -> h' writes safe

  // ---- ew_u -> h'_u into PU ----
#pragma unroll
  for (int m = 0; m < 4; ++m)
#pragma unroll
    for (int r4 = 0; r4 < 4; ++r4) {
      const int row = mbase + m*16 + (l >> 4)*4 + r4;
      const float rr = sigmoid_(aru[m][r4]);
      const float zz = sigmoid_(azu[m][r4]);
      const float nn = tanh_(anu[m][r4] + rr*ahu[m][r4]);
      const float h  = bf2f(s.OU[row][SWZ(row, col)]);
      s.PU[row][SWZ(row, col)] = f2bf((1.0f - zz)*nn + zz*h);
    }

  // ---- item gh + ew_i -> h'_i into PI ----
  {
    f4 ahi[4];
#pragma unroll
    for (int m = 0; m < 4; ++m) ahi[m] = (f4){bhi,bhi,bhi,bhi};
#pragma unroll
    for (int kt = 0; kt < 4; ++kt) {
      b8 fr = *(const b8*)(Wri + (size_t)(14+kt)*FRAG);
      b8 fz = *(const b8*)(Wzi + (size_t)(14+kt)*FRAG);
      b8 fn = *(const b8*)(Wni + (size_t)(14+kt)*FRAG);
#pragma unroll
      for (int m = 0; m < 4; ++m) {
        b8 h = AFRAG(s.OI, mbase + m*16 + lrow, 32*kt + lk);
        ari[m] = MFMA16(h, fr, ari[m]);
        azi[m] = MFMA16(h, fz, azi[m]);
        ahi[m] = MFMA16(h, fn, ahi[m]);
      }
    }
#pragma unroll
    for (int m = 0; m < 4; ++m)
#pragma unroll
      for (int r4 = 0; r4 < 4; ++r4) {
        const int row = mbase + m*16 + (l >> 4)*4 + r4;
        const float rr = sigmoid_(ari[m][r4]);
        const float zz = sigmoid_(azi[m][r4]);
        const float nn = tanh_(ani[m][r4] + rr*ahi[m][r4]);
        const float h  = bf2f(s.OI[row][SWZ(row, col)]);
        s.PI[row][SWZ(row, col)] = f2bf((1.0f - zz)*nn + zz*h);
      }
  }
  __syncthreads();   // B3: h'_u (PU) and h'_i (PI) visible to all waves

  // ---- memory gates: shared gate_w fragments, user+item A streams ----
  {
    const float gb = gate_b[col];
    f4 agu[4], agi[4];
#pragma unroll
    for (int m = 0; m < 4; ++m) { agu[m] = (f4){gb,gb,gb,gb}; agi[m] = agu[m]; }
#pragma unroll
    for (int kt = 0; kt < 8; ++kt) {
      b8 fg = *(const b8*)(WG + (size_t)kt*FRAG);
#pragma unroll
      for (int m = 0; m < 4; ++m) {
        const int row = mbase + m*16 + lrow;
        b8 au = (kt < 4) ? AFRAG(s.OU, row, 32*kt + lk)
                         : AFRAG(s.PU, row, 32*(kt-4) + lk);
        b8 ai = (kt < 4) ? AFRAG(s.OI, row, 32*kt + lk)
                         : AFRAG(s.PI, row, 32*(kt-4) + lk);
        agu[m] = MFMA16(au, fg, agu[m]);
        agi[m] = MFMA16(ai, fg, agi[m]);
      }
    }
    float* __restrict__ outu = d_out + (size_t)CB*CE;
    float* __restrict__ outi = d_out + (size_t)2*CB*CE;
#pragma unroll
    for (int m = 0; m < 4; ++m)
#pragma unroll
      for (int r4 = 0; r4 < 4; ++r4) {
        const int row = mbase + m*16 + (l >> 4)*4 + r4;
        const float gu = sigmoid_(agu[m][r4]);
        const float gi = sigmoid_(agi[m][r4]);
        const float hu  = bf2f(s.OU[row][SWZ(row, col)]);
        const float hpu = bf2f(s.PU[row][SWZ(row, col)]);
        const float hi  = bf2f(s.OI[row][SWZ(row, col)]);
        const float hpi = bf2f(s.PI[row][SWZ(row, col)]);
        NTS(gu*hpu + (1.0f - gu)*hu, &outu[(size_t)(e0 + row)*CE + col]);
        NTS(gi*hpi + (1.0f - gi)*hi, &outi[(size_t)(e0 + row)*CE + col]);
      }
  }
}

extern "C" void kernel_launch(void* const* d_in, const int* in_sizes, int n_in,
                              void* d_out, int out_size, void* d_ws, size_t ws_size,
                              hipStream_t stream) {
  const int*   user_ids   = (const int*)d_in[0];
  const int*   item_ids   = (const int*)d_in[1];
  const float* timestamps = (const float*)d_in[2];
  const float* features   = (const float*)d_in[3];
  const int*   query_time = (const int*)d_in[4];
  const float* memv       = (const float*)d_in[5];
  const float* last_time  = (const float*)d_in[6];
  const float* time_w     = (const float*)d_in[7];
  const float* u_wih = (const float*)d_in[8];
  const float* u_whh = (const float*)d_in[9];
  const float* u_bih = (const float*)d_in[10];
  const float* u_bhh = (const float*)d_in[11];
  const float* i_wih = (const float*)d_in[12];
  const float* i_whh = (const float*)d_in[13];
  const float* i_bih = (const float*)d_in[14];
  const float* i_bhh = (const float*)d_in[15];
  const float* gate_w = (const float*)d_in[16];
  const float* gate_b = (const float*)d_in[17];
  const float* pred_w = (const float*)d_in[18];
  const float* pred_b = (const float*)d_in[19];
  ushort_t* ws = (ushort_t*)d_ws;
  float* out = (float*)d_out;

  prep_weights<<<dim3(256), dim3(256), 0, stream>>>(u_wih, u_whh, i_wih, i_whh,
                                                    gate_w, pred_w, ws);
  jodie_main<<<dim3(CB/EV), dim3(1024), 0, stream>>>(user_ids, item_ids, timestamps,
                                                     features, query_time, memv,
                                                     last_time, time_w,
                                                     u_bih, u_bhh, i_bih, i_bhh,
                                                     gate_b, pred_b, ws, out);
}

// Round 11
// 411.133 us; speedup vs baseline: 1.7672x; 1.4552x over previous
//
#include <hip/hip_runtime.h>
#include <hip/hip_bf16.h>
#include <cstdint>
#include <cstddef>

// Problem constants
#define CNU 500000      // item id offset
#define CB  65536       // batch
#define CE  128         // embedding dim
#define CF  172         // feature dim
#define EV  128         // events per block (8 M-tiles) — halves per-event weight traffic
#define MT  8

typedef unsigned short ushort_t;
typedef __attribute__((ext_vector_type(8))) short b8;    // 8 x bf16
typedef __attribute__((ext_vector_type(4))) float f4;    // MFMA accumulator
typedef __attribute__((ext_vector_type(4))) float f32x4;

#define MFMA16(a,b,c) __builtin_amdgcn_mfma_f32_16x16x32_bf16((a),(b),(c),0,0,0)

#define NTL4(p)   __builtin_nontemporal_load((const f32x4*)(p))
#define NTLI(p)   __builtin_nontemporal_load(p)
#define NTS(v, p) __builtin_nontemporal_store((v), (p))

// ---- packed weight layout in ws (ushort elements), B-fragment order:
// frag(nt,kt): lane l holds B[k=kt*32+(l>>4)*8+j][n=nt*16+(l&15)], j=0..7
#define FRAG 512
#define U_KT 18                   // 14 k-tiles wih (K pad 448) + 4 whh
#define U_NT 24
#define U_SZ (U_NT*U_KT*FRAG)
#define PU_OFF 0
#define PI_OFF U_SZ
#define PG_OFF (2*U_SZ)
#define G_SZ (8*8*FRAG)
#define PP_OFF (PG_OFF + G_SZ)
#define P_SZ (8*4*FRAG)

// XOR-swizzle on 16B granules, both write and read sides (T2 discipline).
#define SWZ(r, c) ((c) ^ (((r) & 7) << 3))
#define AFRAG(T, r, c) (*(const b8*)&(T)[(r)][SWZ((r), (c))])

__device__ __forceinline__ unsigned pk2bf(float a, float b) {
  __hip_bfloat162 h = __float22bfloat162_rn(make_float2(a, b));   // v_cvt_pk_bf16_f32
  return *reinterpret_cast<unsigned*>(&h);
}
__device__ __forceinline__ ushort_t f2bf(float f) {
  unsigned u = __float_as_uint(f);
  return (ushort_t)((u + 0x7FFFu + ((u >> 16) & 1u)) >> 16);   // RNE scalar
}
__device__ __forceinline__ float bf2f(ushort_t h) {
  return __uint_as_float(((unsigned)h) << 16);
}
__device__ __forceinline__ float sigmoid_(float x) { return 1.0f/(1.0f+__expf(-x)); }
__device__ __forceinline__ float tanh_(float x) { float e=__expf(2.0f*x); return 1.0f-2.0f/(e+1.0f); }

// On-the-fly projection — pred phase ONLY (isolated, no live accumulators).
__device__ __forceinline__ b8 scale8(b8 x, float d, f32x4 t0, f32x4 t1) {
  union { ushort_t u[8]; unsigned q[4]; b8 v; } in, out;
  in.v = x;
  const float tt[8] = {t0[0],t0[1],t0[2],t0[3], t1[0],t1[1],t1[2],t1[3]};
#pragma unroll
  for (int j = 0; j < 4; ++j) {
    float a = bf2f(in.u[2*j]);
    float b = bf2f(in.u[2*j+1]);
    a = fmaf(a, d*tt[2*j],   a);
    b = fmaf(b, d*tt[2*j+1], b);
    out.q[j] = pk2bf(a, b);
  }
  return out.v;
}

// Feature A-fragment straight from global fp32 (read-once; no LDS staging).
__device__ __forceinline__ b8 fe_frag(const float* __restrict__ features,
                                      int grow, int kf, int lk) {
  union { unsigned q[4]; b8 v; } r;
  if (kf < 5) {
    const float* fp = features + (size_t)grow*CF + 32*kf + lk;
    const f32x4 x0 = NTL4(fp);
    const f32x4 x1 = NTL4(fp + 4);
    r.q[0] = pk2bf(x0[0], x0[1]);  r.q[1] = pk2bf(x0[2], x0[3]);
    r.q[2] = pk2bf(x1[0], x1[1]);  r.q[3] = pk2bf(x1[2], x1[3]);
  } else {
    float v[8];
#pragma unroll
    for (int j = 0; j < 8; ++j) {
      const int c = 160 + lk + j;
      v[j] = (c < CF) ? features[(size_t)grow*CF + c] : 0.0f;
    }
    r.q[0] = pk2bf(v[0], v[1]);  r.q[1] = pk2bf(v[2], v[3]);
    r.q[2] = pk2bf(v[4], v[5]);  r.q[3] = pk2bf(v[6], v[7]);
  }
  return r.v;
}

// ---- LDS: 132 KB, 1 block/CU, 8 waves (2/SIMD -> 256-reg budget per wave).
// PU/PI staged projected; overwritten by h'_u/h'_i after B2.
struct __align__(16) SLds {
  ushort_t PU[EV][128];   // proj_user -> h'_u after B2
  ushort_t PI[EV][128];   // proj_item -> h'_i after B2
  ushort_t OU[EV][128];   // old_user (h_u)
  ushort_t OI[EV][128];   // old_item (h_i)
  float TW[128];
  float DQ[EV];
};

extern "C" __global__ void prep_weights(
    const float* __restrict__ u_wih, const float* __restrict__ u_whh,
    const float* __restrict__ i_wih, const float* __restrict__ i_whh,
    const float* __restrict__ gate_w, const float* __restrict__ pred_w,
    ushort_t* __restrict__ ws)
{
  const int stride = gridDim.x * blockDim.x;
  const int tid = blockIdx.x * blockDim.x + threadIdx.x;
  for (int i = tid; i < U_SZ; i += stride) {
    const int nt = i / (U_KT*FRAG);
    const int r1 = i - nt*(U_KT*FRAG);
    const int kt = r1 / FRAG;
    const int e  = r1 - kt*FRAG;
    const int l  = e >> 3, j = e & 7;
    const int n  = nt*16 + (l & 15);
    const int k  = (l >> 4)*8 + j;
    float vu, vi;
    if (kt < 14) {
      const int kk = kt*32 + k;
      vu = (kk < 428) ? u_wih[(size_t)n*428 + kk] : 0.0f;
      vi = (kk < 428) ? i_wih[(size_t)n*428 + kk] : 0.0f;
    } else {
      const int kk = (kt - 14)*32 + k;
      vu = u_whh[(size_t)n*128 + kk];
      vi = i_whh[(size_t)n*128 + kk];
    }
    ws[PU_OFF + i] = f2bf(vu);
    ws[PI_OFF + i] = f2bf(vi);
  }
  for (int i = tid; i < G_SZ; i += stride) {
    const int nt = i / (8*FRAG);
    const int r1 = i - nt*(8*FRAG);
    const int kt = r1 / FRAG;
    const int e  = r1 - kt*FRAG;
    const int l  = e >> 3, j = e & 7;
    const int n  = nt*16 + (l & 15);
    const int kk = kt*32 + (l >> 4)*8 + j;
    ws[PG_OFF + i] = f2bf(gate_w[(size_t)n*256 + kk]);
  }
  for (int i = tid; i < P_SZ; i += stride) {
    const int nt = i / (4*FRAG);
    const int r1 = i - nt*(4*FRAG);
    const int kt = r1 / FRAG;
    const int e  = r1 - kt*FRAG;
    const int l  = e >> 3, j = e & 7;
    const int n  = nt*16 + (l & 15);
    const int kk = kt*32 + (l >> 4)*8 + j;
    ws[PP_OFF + i] = f2bf(pred_w[(size_t)n*128 + kk]);
  }
}

extern "C" __global__ void __launch_bounds__(512, 2)
jodie_main(const int* __restrict__ user_ids, const int* __restrict__ item_ids,
           const float* __restrict__ timestamps, const float* __restrict__ features,
           const int* __restrict__ query_time, const float* __restrict__ memv,
           const float* __restrict__ last_time, const float* __restrict__ time_w,
           const float* __restrict__ u_bih, const float* __restrict__ u_bhh,
           const float* __restrict__ i_bih, const float* __restrict__ i_bhh,
           const float* __restrict__ gate_b, const float* __restrict__ pred_b,
           const ushort_t* __restrict__ ws, float* __restrict__ d_out)
{
  __shared__ SLds s;
  const int t  = threadIdx.x;
  const int e0 = blockIdx.x * EV;

  // ---- stage: PU/PI (projected at load) + OU/OI + TW + DQ; 4 passes ----
  if (t < 32) *(float4*)&s.TW[t*4] = *(const float4*)&time_w[t*4];
  {
    const int c8 = (t & 15) * 8;
    const float qt = (float)query_time[0];
    const float4 tw0 = *(const float4*)&time_w[c8];
    const float4 tw1 = *(const float4*)&time_w[c8 + 4];
    const float twv[8] = {tw0.x,tw0.y,tw0.z,tw0.w, tw1.x,tw1.y,tw1.z,tw1.w};
#pragma unroll
    for (int ep = 0; ep < 4; ++ep) {
      const int e  = ep*32 + (t >> 4);
      const int ge = e0 + e;
      const int u   = NTLI(&user_ids[ge]);
      const int itn = NTLI(&item_ids[ge]) + CNU;
      const float ts = NTLI(&timestamps[ge]);
      const float lu = NTLI(&last_time[u]);
      const float li = NTLI(&last_time[itn]);
      const float du = ts - lu, di = ts - li;
      if ((t & 15) == 0) s.DQ[e] = qt - lu;

      const f32x4 ou0 = NTL4(&memv[(size_t)u  *CE + c8]);
      const f32x4 ou1 = NTL4(&memv[(size_t)u  *CE + c8 + 4]);
      const f32x4 oi0 = NTL4(&memv[(size_t)itn*CE + c8]);
      const f32x4 oi1 = NTL4(&memv[(size_t)itn*CE + c8 + 4]);
      const float ouv[8] = {ou0[0],ou0[1],ou0[2],ou0[3], ou1[0],ou1[1],ou1[2],ou1[3]};
      const float oiv[8] = {oi0[0],oi0[1],oi0[2],oi0[3], oi1[0],oi1[1],oi1[2],oi1[3]};

      union U8 { unsigned q[4]; b8 v; };
      U8 xu, xi, hu, hi;
#pragma unroll
      for (int j = 0; j < 8; j += 2) {
        xu.q[j>>1] = pk2bf(ouv[j]*(1.0f + du*twv[j]), ouv[j+1]*(1.0f + du*twv[j+1]));
        xi.q[j>>1] = pk2bf(oiv[j]*(1.0f + di*twv[j]), oiv[j+1]*(1.0f + di*twv[j+1]));
        hu.q[j>>1] = pk2bf(ouv[j], ouv[j+1]);
        hi.q[j>>1] = pk2bf(oiv[j], oiv[j+1]);
      }
      *(b8*)&s.PU[e][SWZ(e, c8)] = xu.v;
      *(b8*)&s.PI[e][SWZ(e, c8)] = xi.v;
      *(b8*)&s.OU[e][SWZ(e, c8)] = hu.v;
      *(b8*)&s.OI[e][SWZ(e, c8)] = hi.v;
    }
  }
  __syncthreads();   // B1

  const int wv   = t >> 6, l = t & 63;
  const int lrow = l & 15;
  const int lk   = (l >> 4) * 8;
  const int col  = wv*16 + lrow;

  const ushort_t* Wru = ws + PU_OFF + (size_t)(wv     )*U_KT*FRAG + l*8;
  const ushort_t* Wzu = ws + PU_OFF + (size_t)(wv +  8)*U_KT*FRAG + l*8;
  const ushort_t* Wnu = ws + PU_OFF + (size_t)(wv + 16)*U_KT*FRAG + l*8;
  const ushort_t* Wri = ws + PI_OFF + (size_t)(wv     )*U_KT*FRAG + l*8;
  const ushort_t* Wzi = ws + PI_OFF + (size_t)(wv +  8)*U_KT*FRAG + l*8;
  const ushort_t* Wni = ws + PI_OFF + (size_t)(wv + 16)*U_KT*FRAG + l*8;

  // ---- pred: qu built on the fly from OU (isolated phase, no live accs) ----
  {
    const float bp = pred_b[col];
    const ushort_t* WP = ws + PP_OFF + (size_t)wv*4*FRAG + l*8;
    f4 ap[MT];
#pragma unroll
    for (int m = 0; m < MT; ++m) ap[m] = (f4){bp,bp,bp,bp};
#pragma unroll
    for (int kt = 0; kt < 4; ++kt) {
      b8 fp = *(const b8*)(WP + (size_t)kt*FRAG);
      const f32x4 t0 = *(const f32x4*)&s.TW[32*kt + lk];
      const f32x4 t1 = *(const f32x4*)&s.TW[32*kt + lk + 4];
#pragma unroll
      for (int m = 0; m < MT; ++m) {
        const int row = m*16 + lrow;
        b8 a = scale8(AFRAG(s.OU, row, 32*kt + lk), s.DQ[row], t0, t1);
        ap[m] = MFMA16(a, fp, ap[m]);
      }
    }
#pragma unroll
    for (int m = 0; m < MT; ++m)
#pragma unroll
      for (int r4 = 0; r4 < 4; ++r4) {
        const int row = m*16 + (l >> 4)*4 + r4;
        NTS(ap[m][r4], &d_out[(size_t)(e0 + row)*CE + col]);
      }
  }

  unsigned hpu_pk[2*MT], hpi_pk[2*MT];   // packed h' (2 bf16 per u32)

  // ================= USER GRU (4 acc arrays x MT=8 = 128 acc regs) =========
  {
    const float br = u_bih[col]     + u_bhh[col];
    const float bz = u_bih[col+128] + u_bhh[col+128];
    const float bn = u_bih[col+256];
    const float bh = u_bhh[col+256];
    f4 ar[MT], az[MT], an8[MT], ah[MT];
#pragma unroll
    for (int m = 0; m < MT; ++m) {
      ar[m] = (f4){br,br,br,br};   az[m] = (f4){bz,bz,bz,bz};
      an8[m] = (f4){bn,bn,bn,bn};  ah[m] = (f4){bh,bh,bh,bh};
    }
#pragma unroll
    for (int kt = 0; kt < 4; ++kt) {   // x part 1: proj_user (LDS)
      b8 fr = *(const b8*)(Wru + (size_t)kt*FRAG);
      b8 fz = *(const b8*)(Wzu + (size_t)kt*FRAG);
      b8 fn = *(const b8*)(Wnu + (size_t)kt*FRAG);
#pragma unroll
      for (int m = 0; m < MT; ++m) {
        b8 a = AFRAG(s.PU, m*16 + lrow, 32*kt + lk);
        ar[m] = MFMA16(a, fr, ar[m]);  az[m] = MFMA16(a, fz, az[m]);
        an8[m] = MFMA16(a, fn, an8[m]);
      }
    }
#pragma unroll
    for (int kt = 0; kt < 4; ++kt) {   // x part 2: proj_item (LDS), weight kt+4
      b8 fr = *(const b8*)(Wru + (size_t)(kt+4)*FRAG);
      b8 fz = *(const b8*)(Wzu + (size_t)(kt+4)*FRAG);
      b8 fn = *(const b8*)(Wnu + (size_t)(kt+4)*FRAG);
#pragma unroll
      for (int m = 0; m < MT; ++m) {
        b8 a = AFRAG(s.PI, m*16 + lrow, 32*kt + lk);
        ar[m] = MFMA16(a, fr, ar[m]);  az[m] = MFMA16(a, fz, az[m]);
        an8[m] = MFMA16(a, fn, an8[m]);
      }
    }
#pragma unroll
    for (int kf = 0; kf < 6; ++kf) {   // x part 3: features (global), weight kf+8
      b8 fr = *(const b8*)(Wru + (size_t)(kf+8)*FRAG);
      b8 fz = *(const b8*)(Wzu + (size_t)(kf+8)*FRAG);
      b8 fn = *(const b8*)(Wnu + (size_t)(kf+8)*FRAG);
#pragma unroll
      for (int m = 0; m < MT; ++m) {
        b8 a = fe_frag(features, e0 + m*16 + lrow, kf, lk);
        ar[m] = MFMA16(a, fr, ar[m]);  az[m] = MFMA16(a, fz, az[m]);
        an8[m] = MFMA16(a, fn, an8[m]);
      }
    }
#pragma unroll
    for (int kt = 0; kt < 4; ++kt) {   // gh over OU, weight kt+14
      b8 fr = *(const b8*)(Wru + (size_t)(14+kt)*FRAG);
      b8 fz = *(const b8*)(Wzu + (size_t)(14+kt)*FRAG);
      b8 fn = *(const b8*)(Wnu + (size_t)(14+kt)*FRAG);
#pragma unroll
      for (int m = 0; m < MT; ++m) {
        b8 h = AFRAG(s.OU, m*16 + lrow, 32*kt + lk);
        ar[m] = MFMA16(h, fr, ar[m]);  az[m] = MFMA16(h, fz, az[m]);
        ah[m] = MFMA16(h, fn, ah[m]);
      }
    }
    // ew -> packed regs (PU still live for item gi; write deferred past B2)
#pragma unroll
    for (int m = 0; m < MT; ++m) {
      float hp[4];
#pragma unroll
      for (int r4 = 0; r4 < 4; ++r4) {
        const int row = m*16 + (l >> 4)*4 + r4;
        const float rr = sigmoid_(ar[m][r4]);
        const float zz = sigmoid_(az[m][r4]);
        const float nn = tanh_(an8[m][r4] + rr*ah[m][r4]);
        const float h  = bf2f(s.OU[row][SWZ(row, col)]);
        hp[r4] = (1.0f - zz)*nn + zz*h;
      }
      hpu_pk[2*m]   = pk2bf(hp[0], hp[1]);
      hpu_pk[2*m+1] = pk2bf(hp[2], hp[3]);
    }
  }

  // ================= ITEM GRU =================
  {
    const float br = i_bih[col]     + i_bhh[col];
    const float bz = i_bih[col+128] + i_bhh[col+128];
    const float bn = i_bih[col+256];
    const float bh = i_bhh[col+256];
    f4 ar[MT], az[MT], an8[MT], ah[MT];
#pragma unroll
    for (int m = 0; m < MT; ++m) {
      ar[m] = (f4){br,br,br,br};   az[m] = (f4){bz,bz,bz,bz};
      an8[m] = (f4){bn,bn,bn,bn};  ah[m] = (f4){bh,bh,bh,bh};
    }
#pragma unroll
    for (int kt = 0; kt < 4; ++kt) {   // x part 1: proj_item (LDS)
      b8 fr = *(const b8*)(Wri + (size_t)kt*FRAG);
      b8 fz = *(const b8*)(Wzi + (size_t)kt*FRAG);
      b8 fn = *(const b8*)(Wni + (size_t)kt*FRAG);
#pragma unroll
      for (int m = 0; m < MT; ++m) {
        b8 a = AFRAG(s.PI, m*16 + lrow, 32*kt + lk);
        ar[m] = MFMA16(a, fr, ar[m]);  az[m] = MFMA16(a, fz, az[m]);
        an8[m] = MFMA16(a, fn, an8[m]);
      }
    }
#pragma unroll
    for (int kt = 0; kt < 4; ++kt) {   // x part 2: proj_user (LDS), weight kt+4
      b8 fr = *(const b8*)(Wri + (size_t)(kt+4)*FRAG);
      b8 fz = *(const b8*)(Wzi + (size_t)(kt+4)*FRAG);
      b8 fn = *(const b8*)(Wni + (size_t)(kt+4)*FRAG);
#pragma unroll
      for (int m = 0; m < MT; ++m) {
        b8 a = AFRAG(s.PU, m*16 + lrow, 32*kt + lk);
        ar[m] = MFMA16(a, fr, ar[m]);  az[m] = MFMA16(a, fz, az[m]);
        an8[m] = MFMA16(a, fn, an8[m]);
      }
    }
#pragma unroll
    for (int kf = 0; kf < 6; ++kf) {   // x part 3: features (global), weight kf+8
      b8 fr = *(const b8*)(Wri + (size_t)(kf+8)*FRAG);
      b8 fz = *(const b8*)(Wzi + (size_t)(kf+8)*FRAG);
      b8 fn = *(const b8*)(Wni + (size_t)(kf+8)*FRAG);
#pragma unroll
      for (int m = 0; m < MT; ++m) {
        b8 a = fe_frag(features, e0 + m*16 + lrow, kf, lk);
        ar[m] = MFMA16(a, fr, ar[m]);  az[m] = MFMA16(a, fz, az[m]);
        an8[m] = MFMA16(a, fn, an8[m]);
      }
    }
#pragma unroll
    for (int kt = 0; kt < 4; ++kt) {   // gh over OI, weight kt+14
      b8 fr = *(const b8*)(Wri + (size_t)(14+kt)*FRAG);
      b8 fz = *(const b8*)(Wzi + (size_t)(14+kt)*FRAG);
      b8 fn = *(const b8*)(Wni + (size_t)(14+kt)*FRAG);
#pragma unroll
      for (int m = 0; m < MT; ++m) {
        b8 h = AFRAG(s.OI, m*16 + lrow, 32*kt + lk);
        ar[m] = MFMA16(h, fr, ar[m]);  az[m] = MFMA16(h, fz, az[m]);
        ah[m] = MFMA16(h, fn, ah[m]);
      }
    }
#pragma unroll
    for (int m = 0; m < MT; ++m) {
      float hp[4];
#pragma unroll
      for (int r4 = 0; r4 < 4; ++r4) {
        const int row = m*16 + (l >> 4)*4 + r4;
        const float rr = sigmoid_(ar[m][r4]);
        const float zz = sigmoid_(az[m][r4]);
        const float nn = tanh_(an8[m][r4] + rr*ah[m][r4]);
        const float h  = bf2f(s.OI[row][SWZ(row, col)]);
        hp[r4] = (1.0f - zz)*nn + zz*h;
      }
      hpi_pk[2*m]   = pk2bf(hp[0], hp[1]);
      hpi_pk[2*m+1] = pk2bf(hp[2], hp[3]);
    }
  }
  __syncthreads();   // B2: all gi reads of PU/PI complete

  // ---- write h'_u -> PU, h'_i -> PI ----
#pragma unroll
  for (int m = 0; m < MT; ++m)
#pragma unroll
    for (int r4 = 0; r4 < 4; ++r4) {
      const int row = m*16 + (l >> 4)*4 + r4;
      const unsigned qu_ = hpu_pk[2*m + (r4 >> 1)];
      const unsigned qi_ = hpi_pk[2*m + (r4 >> 1)];
      const ushort_t vu = (r4 & 1) ? (ushort_t)(qu_ >> 16) : (ushort_t)(qu_ & 0xFFFF);
      const ushort_t vi = (r4 & 1) ? (ushort_t)(qi_ >> 16) : (ushort_t)(qi_ & 0xFFFF);
      s.PU[row][SWZ(row, col)] = vu;
      s.PI[row][SWZ(row, col)] = vi;
    }
  __syncthreads();   // B3: h' visible to all waves

  // ---- memory gates: shared gate_w fragments, user+item A streams ----
  {
    const float gb = gate_b[col];
    const ushort_t* WG = ws + PG_OFF + (size_t)wv*8*FRAG + l*8;
    f4 agu[MT], agi[MT];
#pragma unroll
    for (int m = 0; m < MT; ++m) { agu[m] = (f4){gb,gb,gb,gb}; agi[m] = agu[m]; }
#pragma unroll
    for (int kt = 0; kt < 8; ++kt) {
      b8 fg = *(const b8*)(WG + (size_t)kt*FRAG);
#pragma unroll
      for (int m = 0; m < MT; ++m) {
        const int row = m*16 + lrow;
        b8 au = (kt < 4) ? AFRAG(s.OU, row, 32*kt + lk)
                         : AFRAG(s.PU, row, 32*(kt-4) + lk);
        b8 ai = (kt < 4) ? AFRAG(s.OI, row, 32*kt + lk)
                         : AFRAG(s.PI, row, 32*(kt-4) + lk);
        agu[m] = MFMA16(au, fg, agu[m]);
        agi[m] = MFMA16(ai, fg, agi[m]);
      }
    }
    float* __restrict__ outu = d_out + (size_t)CB*CE;
    float* __restrict__ outi = d_out + (size_t)2*CB*CE;
#pragma unroll
    for (int m = 0; m < MT; ++m)
#pragma unroll
      for (int r4 = 0; r4 < 4; ++r4) {
        const int row = m*16 + (l >> 4)*4 + r4;
        const float gu = sigmoid_(agu[m][r4]);
        const float gi = sigmoid_(agi[m][r4]);
        const float hu  = bf2f(s.OU[row][SWZ(row, col)]);
        const float hpu = bf2f(s.PU[row][SWZ(row, col)]);
        const float hi  = bf2f(s.OI[row][SWZ(row, col)]);
        const float hpi = bf2f(s.PI[row][SWZ(row, col)]);
        NTS(gu*hpu + (1.0f - gu)*hu, &outu[(size_t)(e0 + row)*CE + col]);
        NTS(gi*hpi + (1.0f - gi)*hi, &outi[(size_t)(e0 + row)*CE + col]);
      }
  }
}

extern "C" void kernel_launch(void* const* d_in, const int* in_sizes, int n_in,
                              void* d_out, int out_size, void* d_ws, size_t ws_size,
                              hipStream_t stream) {
  const int*   user_ids   = (const int*)d_in[0];
  const int*   item_ids   = (const int*)d_in[1];
  const float* timestamps = (const float*)d_in[2];
  const float* features   = (const float*)d_in[3];
  const int*   query_time = (const int*)d_in[4];
  const float* memv       = (const float*)d_in[5];
  const float* last_time  = (const float*)d_in[6];
  const float* time_w     = (const float*)d_in[7];
  const float* u_wih = (const float*)d_in[8];
  const float* u_whh = (const float*)d_in[9];
  const float* u_bih = (const float*)d_in[10];
  const float* u_bhh = (const float*)d_in[11];
  const float* i_wih = (const float*)d_in[12];
  const float* i_whh = (const float*)d_in[13];
  const float* i_bih = (const float*)d_in[14];
  const float* i_bhh = (const float*)d_in[15];
  const float* gate_w = (const float*)d_in[16];
  const float* gate_b = (const float*)d_in[17];
  const float* pred_w = (const float*)d_in[18];
  const float* pred_b = (const float*)d_in[19];
  ushort_t* ws = (ushort_t*)d_ws;
  float* out = (float*)d_out;

  prep_weights<<<dim3(256), dim3(256), 0, stream>>>(u_wih, u_whh, i_wih, i_whh,
                                                    gate_w, pred_w, ws);
  jodie_main<<<dim3(CB/EV), dim3(512), 0, stream>>>(user_ids, item_ids, timestamps,
                                                    features, query_time, memv,
                                                    last_time, time_w,
                                                    u_bih, u_bhh, i_bih, i_bhh,
                                                    gate_b, pred_b, ws, out);
}

// Round 12
// 164.538 us; speedup vs baseline: 4.4158x; 2.4987x over previous
//
#include <hip/hip_runtime.h>
#include <hip/hip_bf16.h>
#include <cstdint>
#include <cstddef>

// Problem constants
#define CNU 500000      // item id offset
#define CB  65536       // batch
#define CE  128         // embedding dim
#define CF  172         // feature dim
#define EV  64          // events per B-block (4 M-tiles)
#define SECB ((size_t)CB*CE*4)   // bytes per output section (33,554,432)

typedef unsigned short ushort_t;
typedef __attribute__((ext_vector_type(8))) short b8;    // 8 x bf16
typedef __attribute__((ext_vector_type(4))) float f4;    // MFMA accumulator
typedef __attribute__((ext_vector_type(4))) float f32x4;

#define MFMA16(a,b,c) __builtin_amdgcn_mfma_f32_16x16x32_bf16((a),(b),(c),0,0,0)

#define NTL4(p)   __builtin_nontemporal_load((const f32x4*)(p))
#define NTLI(p)   __builtin_nontemporal_load(p)
#define NTS(v, p) __builtin_nontemporal_store((v), (p))

// ---- packed weight layout in ws (ushort elements), B-fragment order:
// frag(nt,kt): lane l holds B[k=kt*32+(l>>4)*8+j][n=nt*16+(l&15)], j=0..7
#define FRAG 512
#define U_KT 18                   // 14 k-tiles wih (K pad 448) + 4 whh
#define U_NT 24
#define U_SZ (U_NT*U_KT*FRAG)
#define PU_OFF 0
#define PI_OFF U_SZ
#define PG_OFF (2*U_SZ)
#define G_SZ (8*8*FRAG)
#define PP_OFF (PG_OFF + G_SZ)
#define P_SZ (8*4*FRAG)

// Row-major XOR swizzle (only for the h' round-trip tiles HU/HI).
#define SWZ(r, c) ((c) ^ (((r) & 7) << 3))
#define AFRAG(T, r, c) (*(const b8*)&(T)[(r)][SWZ((r), (c))])
// Fragment-ordered LDS read (canonical conflict-free path: lane l reads bytes l*16).
#define FR(T, kt, m) (*(const b8*)&(T)[(((kt)*4 + (m))*512) + l*8])

__device__ __forceinline__ unsigned pk2bf(float a, float b) {
  __hip_bfloat162 h = __float22bfloat162_rn(make_float2(a, b));   // v_cvt_pk_bf16_f32
  return *reinterpret_cast<unsigned*>(&h);
}
__device__ __forceinline__ ushort_t f2bf(float f) {
  unsigned u = __float_as_uint(f);
  return (ushort_t)((u + 0x7FFFu + ((u >> 16) & 1u)) >> 16);   // RNE scalar
}
__device__ __forceinline__ float bf2f(ushort_t h) {
  return __uint_as_float(((unsigned)h) << 16);
}
__device__ __forceinline__ float sigmoid_(float x) { return 1.0f/(1.0f+__expf(-x)); }
__device__ __forceinline__ float tanh_(float x) { float e=__expf(2.0f*x); return 1.0f-2.0f/(e+1.0f); }

// On-the-fly projection (pred only; verified numerics in R11).
__device__ __forceinline__ b8 scale8(b8 x, float d, f32x4 t0, f32x4 t1) {
  union { ushort_t u[8]; unsigned q[4]; b8 v; } in, out;
  in.v = x;
  const float tt[8] = {t0[0],t0[1],t0[2],t0[3], t1[0],t1[1],t1[2],t1[3]};
#pragma unroll
  for (int j = 0; j < 4; ++j) {
    float a = bf2f(in.u[2*j]);
    float b = bf2f(in.u[2*j+1]);
    a = fmaf(a, d*tt[2*j],   a);
    b = fmaf(b, d*tt[2*j+1], b);
    out.q[j] = pk2bf(a, b);
  }
  return out.v;
}

// Element (row,col) of a fragment-ordered tile.
__device__ __forceinline__ float frag_elem(const ushort_t* T, int row, int col) {
  const int kt = col >> 5, q = (col & 31) >> 3, j = col & 7;
  return bf2f(T[(size_t)((kt*4 + (row >> 4))*512 + ((row & 15) + 16*q)*8 + j)]);
}

extern "C" __global__ void prep_weights(
    const float* __restrict__ u_wih, const float* __restrict__ u_whh,
    const float* __restrict__ i_wih, const float* __restrict__ i_whh,
    const float* __restrict__ gate_w, const float* __restrict__ pred_w,
    ushort_t* __restrict__ ws)
{
  const int stride = gridDim.x * blockDim.x;
  const int tid = blockIdx.x * blockDim.x + threadIdx.x;
  for (int i = tid; i < U_SZ; i += stride) {
    const int nt = i / (U_KT*FRAG);
    const int r1 = i - nt*(U_KT*FRAG);
    const int kt = r1 / FRAG;
    const int e  = r1 - kt*FRAG;
    const int l  = e >> 3, j = e & 7;
    const int n  = nt*16 + (l & 15);
    const int k  = (l >> 4)*8 + j;
    float vu, vi;
    if (kt < 14) {
      const int kk = kt*32 + k;
      vu = (kk < 428) ? u_wih[(size_t)n*428 + kk] : 0.0f;
      vi = (kk < 428) ? i_wih[(size_t)n*428 + kk] : 0.0f;
    } else {
      const int kk = (kt - 14)*32 + k;
      vu = u_whh[(size_t)n*128 + kk];
      vi = i_whh[(size_t)n*128 + kk];
    }
    ws[PU_OFF + i] = f2bf(vu);
    ws[PI_OFF + i] = f2bf(vi);
  }
  for (int i = tid; i < G_SZ; i += stride) {
    const int nt = i / (8*FRAG);
    const int r1 = i - nt*(8*FRAG);
    const int kt = r1 / FRAG;
    const int e  = r1 - kt*FRAG;
    const int l  = e >> 3, j = e & 7;
    const int n  = nt*16 + (l & 15);
    const int kk = kt*32 + (l >> 4)*8 + j;
    ws[PG_OFF + i] = f2bf(gate_w[(size_t)n*256 + kk]);
  }
  for (int i = tid; i < P_SZ; i += stride) {
    const int nt = i / (4*FRAG);
    const int r1 = i - nt*(4*FRAG);
    const int kt = r1 / FRAG;
    const int e  = r1 - kt*FRAG;
    const int l  = e >> 3, j = e & 7;
    const int n  = nt*16 + (l & 15);
    const int kk = kt*32 + (l >> 4)*8 + j;
    ws[PP_OFF + i] = f2bf(pred_w[(size_t)n*128 + kk]);
  }
}

// ===== Kernel A: gather + project + convert -> staged fragments in d_out =====
// Staged layout per B-block bb (64 events), inside the 3 output windows:
//   W0 = pred_sec + bb*32KB : PU frags [16KB] | PI frags [16KB]
//   W1 = user_sec + bb*32KB : OU frags [16KB] | OI frags [16KB]
//   W2 = item_sec + bb*32KB : FE frags [24KB] | DQ [256B] | (unused tail)
// Kernel B copies these to LDS before writing any output over them.
extern "C" __global__ void __launch_bounds__(512, 4)
stage_gather(const int* __restrict__ user_ids, const int* __restrict__ item_ids,
             const float* __restrict__ timestamps, const float* __restrict__ features,
             const int* __restrict__ query_time, const float* __restrict__ memv,
             const float* __restrict__ last_time, const float* __restrict__ time_w,
             char* __restrict__ outb)
{
  const int t  = threadIdx.x;
  const int e0 = blockIdx.x * 32;          // 32 events/block, grid 2048
  {
    const int c8 = (t & 15) * 8;
    const int e  = t >> 4;
    const int ge = e0 + e;
    const int bb = ge >> 6, e64 = ge & 63;
    const int mt = e64 >> 4, row = e64 & 15;
    const int kt = c8 >> 5, q = (c8 & 31) >> 3;
    const size_t fo = (size_t)(((kt*4 + mt)*512 + (row + 16*q)*8) * 2);

    const int u   = NTLI(&user_ids[ge]);
    const int itn = NTLI(&item_ids[ge]) + CNU;
    const float ts = NTLI(&timestamps[ge]);
    const float lu = last_time[u];
    const float li = last_time[itn];
    const float qt = (float)query_time[0];
    const float du = ts - lu, di = ts - li;

    const float4 tw0 = *(const float4*)&time_w[c8];
    const float4 tw1 = *(const float4*)&time_w[c8 + 4];
    const float twv[8] = {tw0.x,tw0.y,tw0.z,tw0.w, tw1.x,tw1.y,tw1.z,tw1.w};
    const f32x4 ou0 = NTL4(&memv[(size_t)u  *CE + c8]);
    const f32x4 ou1 = NTL4(&memv[(size_t)u  *CE + c8 + 4]);
    const f32x4 oi0 = NTL4(&memv[(size_t)itn*CE + c8]);
    const f32x4 oi1 = NTL4(&memv[(size_t)itn*CE + c8 + 4]);
    const float ouv[8] = {ou0[0],ou0[1],ou0[2],ou0[3], ou1[0],ou1[1],ou1[2],ou1[3]};
    const float oiv[8] = {oi0[0],oi0[1],oi0[2],oi0[3], oi1[0],oi1[1],oi1[2],oi1[3]};

    union U8 { unsigned q_[4]; b8 v; };
    U8 xu, xi, hu, hi;
#pragma unroll
    for (int j = 0; j < 8; j += 2) {
      xu.q_[j>>1] = pk2bf(ouv[j]*(1.0f + du*twv[j]), ouv[j+1]*(1.0f + du*twv[j+1]));
      xi.q_[j>>1] = pk2bf(oiv[j]*(1.0f + di*twv[j]), oiv[j+1]*(1.0f + di*twv[j+1]));
      hu.q_[j>>1] = pk2bf(ouv[j], ouv[j+1]);
      hi.q_[j>>1] = pk2bf(oiv[j], oiv[j+1]);
    }
    char* W0 = outb + (size_t)bb*32768;
    char* W1 = outb + SECB + (size_t)bb*32768;
    *(b8*)(W0 + fo)         = xu.v;   // PU
    *(b8*)(W0 + 16384 + fo) = xi.v;   // PI
    *(b8*)(W1 + fo)         = hu.v;   // OU
    *(b8*)(W1 + 16384 + fo) = hi.v;   // OI
    if ((t & 15) == 0)
      *(float*)(outb + 2*SECB + (size_t)bb*32768 + 24576 + (size_t)e64*4) = qt - lu;
  }
  // features -> fragment order (24 chunks of 8 cols per event)
  for (int i = t; i < 32*24; i += 512) {
    const int e = i / 24, c = i - e*24;
    const int fkt = c >> 2, fq = c & 3;
    const int ge = e0 + e;
    const int bb = ge >> 6, e64 = ge & 63;
    const int mt = e64 >> 4, row = e64 & 15;
    const int col0 = fkt*32 + fq*8;
    float v[8];
    if (col0 + 8 <= CF) {
      const f32x4 x0 = NTL4(&features[(size_t)ge*CF + col0]);
      const f32x4 x1 = NTL4(&features[(size_t)ge*CF + col0 + 4]);
      v[0]=x0[0]; v[1]=x0[1]; v[2]=x0[2]; v[3]=x0[3];
      v[4]=x1[0]; v[5]=x1[1]; v[6]=x1[2]; v[7]=x1[3];
    } else {
#pragma unroll
      for (int j = 0; j < 8; ++j) {
        const int cc = col0 + j;
        v[j] = (cc < CF) ? features[(size_t)ge*CF + cc] : 0.0f;
      }
    }
    union { unsigned q_[4]; b8 v8; } fb;
    fb.q_[0] = pk2bf(v[0], v[1]);  fb.q_[1] = pk2bf(v[2], v[3]);
    fb.q_[2] = pk2bf(v[4], v[5]);  fb.q_[3] = pk2bf(v[6], v[7]);
    *(b8*)(outb + 2*SECB + (size_t)bb*32768
           + (size_t)(((fkt*4 + mt)*512 + (row + 16*fq)*8) * 2)) = fb.v8;
  }
}

// ===== Kernel B: bulk LDS copy + fused MFMA program (R4 structure) =====
struct __align__(16) SLdsB {
  ushort_t PU[8192];     // 16 KB frag-ordered (W0 first half)
  ushort_t PI[8192];     // 16 KB (W0 second half)
  ushort_t OU[8192];     // 16 KB (W1 first half)
  ushort_t OI[8192];     // 16 KB (W1 second half)
  ushort_t FE[12288];    // 24 KB (W2)
  float    DQ[64];       // 256 B (W2 + 24576)
  char     pad2[32768 - 24576 - 256];
  ushort_t HU[EV][128];  // 16 KB row-major XOR (h'_u)
  ushort_t HI[EV][128];  // 16 KB (h'_i)
  float    TW[128];
};                       // 131,584 B -> 1 block/CU

extern "C" __global__ void __launch_bounds__(512, 2)
jodie_main(const float* __restrict__ time_w,
           const float* __restrict__ u_bih, const float* __restrict__ u_bhh,
           const float* __restrict__ i_bih, const float* __restrict__ i_bhh,
           const float* __restrict__ gate_b, const float* __restrict__ pred_b,
           const ushort_t* __restrict__ ws, float* __restrict__ d_out)
{
  __shared__ SLdsB s;
  const int t  = threadIdx.x;
  const int e0 = blockIdx.x * EV;
  char* outb = (char*)d_out;

  // ---- bulk copy staged windows -> LDS (96 KB; 12 b128 chunks/thread) ----
  {
    const char* W0 = outb + (size_t)blockIdx.x*32768;
    const char* W1 = outb + SECB + (size_t)blockIdx.x*32768;
    const char* W2 = outb + 2*SECB + (size_t)blockIdx.x*32768;
    char* lb = (char*)&s;
#pragma unroll
    for (int k = 0; k < 12; ++k) {
      const int idx = k*512 + t;
      const char* src = (idx < 2048) ? (W0 + (size_t)idx*16)
                      : (idx < 4096) ? (W1 + (size_t)(idx - 2048)*16)
                                     : (W2 + (size_t)(idx - 4096)*16);
      *(b8*)(lb + (size_t)idx*16) = *(const b8*)src;
    }
  }
  if (t < 32) *(float4*)&s.TW[t*4] = *(const float4*)&time_w[t*4];
  __syncthreads();   // B1: all staged data in LDS; outputs may now overwrite

  const int wv   = t >> 6, l = t & 63;
  const int lrow = l & 15;
  const int lk   = (l >> 4) * 8;
  const int col  = wv*16 + lrow;

  const ushort_t* Wru = ws + PU_OFF + (size_t)(wv     )*U_KT*FRAG + l*8;
  const ushort_t* Wzu = ws + PU_OFF + (size_t)(wv +  8)*U_KT*FRAG + l*8;
  const ushort_t* Wnu = ws + PU_OFF + (size_t)(wv + 16)*U_KT*FRAG + l*8;
  const ushort_t* Wri = ws + PI_OFF + (size_t)(wv     )*U_KT*FRAG + l*8;
  const ushort_t* Wzi = ws + PI_OFF + (size_t)(wv +  8)*U_KT*FRAG + l*8;
  const ushort_t* Wni = ws + PI_OFF + (size_t)(wv + 16)*U_KT*FRAG + l*8;

  // ---- pred: qu = OU*(1+dq*tw) built on the fly ----
  {
    const float bp = pred_b[col];
    const ushort_t* WP = ws + PP_OFF + (size_t)wv*4*FRAG + l*8;
    f4 ap[4];
#pragma unroll
    for (int m = 0; m < 4; ++m) ap[m] = (f4){bp,bp,bp,bp};
#pragma unroll
    for (int kt = 0; kt < 4; ++kt) {
      b8 fp = *(const b8*)(WP + (size_t)kt*FRAG);
      const f32x4 t0 = *(const f32x4*)&s.TW[32*kt + lk];
      const f32x4 t1 = *(const f32x4*)&s.TW[32*kt + lk + 4];
#pragma unroll
      for (int m = 0; m < 4; ++m) {
        b8 a = scale8(FR(s.OU, kt, m), s.DQ[m*16 + lrow], t0, t1);
        ap[m] = MFMA16(a, fp, ap[m]);
      }
    }
#pragma unroll
    for (int m = 0; m < 4; ++m)
#pragma unroll
      for (int r4 = 0; r4 < 4; ++r4) {
        const int row = m*16 + (l >> 4)*4 + r4;
        NTS(ap[m][r4], &d_out[(size_t)(e0 + row)*CE + col]);
      }
  }

  // ---- biases ----
  const float bru = u_bih[col]     + u_bhh[col];
  const float bzu = u_bih[col+128] + u_bhh[col+128];
  const float bnu = u_bih[col+256];
  const float bhu = u_bhh[col+256];
  const float bri = i_bih[col]     + i_bhh[col];
  const float bzi = i_bih[col+128] + i_bhh[col+128];
  const float bni = i_bih[col+256];
  const float bhi = i_bhh[col+256];

  f4 aru[4], azu[4], anu[4], ari[4], azi[4], ani[4];
#pragma unroll
  for (int m = 0; m < 4; ++m) {
    aru[m] = (f4){bru,bru,bru,bru};  azu[m] = (f4){bzu,bzu,bzu,bzu};
    anu[m] = (f4){bnu,bnu,bnu,bnu};  ari[m] = (f4){bri,bri,bri,bri};
    azi[m] = (f4){bzi,bzi,bzi,bzi};  ani[m] = (f4){bni,bni,bni,bni};
  }

  // ---- FUSED gi: each fragment feeds user (ktu) and item (kti) ----
#define GI_STEP(TILE, pf, ktu, kti)                                          \
  {                                                                          \
    b8 a_[4];                                                                \
    _Pragma("unroll")                                                        \
    for (int m = 0; m < 4; ++m) a_[m] = FR(TILE, pf, m);                     \
    b8 fru = *(const b8*)(Wru + (size_t)(ktu)*FRAG);                         \
    b8 fzu = *(const b8*)(Wzu + (size_t)(ktu)*FRAG);                         \
    b8 fnu = *(const b8*)(Wnu + (size_t)(ktu)*FRAG);                         \
    b8 fri = *(const b8*)(Wri + (size_t)(kti)*FRAG);                         \
    b8 fzi = *(const b8*)(Wzi + (size_t)(kti)*FRAG);                         \
    b8 fni = *(const b8*)(Wni + (size_t)(kti)*FRAG);                         \
    _Pragma("unroll")                                                        \
    for (int m = 0; m < 4; ++m) {                                            \
      aru[m] = MFMA16(a_[m], fru, aru[m]);                                   \
      azu[m] = MFMA16(a_[m], fzu, azu[m]);                                   \
      anu[m] = MFMA16(a_[m], fnu, anu[m]);                                   \
      ari[m] = MFMA16(a_[m], fri, ari[m]);                                   \
      azi[m] = MFMA16(a_[m], fzi, azi[m]);                                   \
      ani[m] = MFMA16(a_[m], fni, ani[m]);                                   \
    }                                                                        \
  }

#pragma unroll
  for (int pf = 0; pf < 4; ++pf) GI_STEP(s.PU, pf, pf, pf + 4)
#pragma unroll
  for (int pf = 0; pf < 4; ++pf) GI_STEP(s.PI, pf, pf + 4, pf)
#pragma unroll
  for (int pf = 0; pf < 6; ++pf) GI_STEP(s.FE, pf, pf + 8, pf + 8)
#undef GI_STEP

  // ---- user gh (K=128) + ew -> h'_u into HU ----
  {
    f4 ah[4];
#pragma unroll
    for (int m = 0; m < 4; ++m) ah[m] = (f4){bhu,bhu,bhu,bhu};
#pragma unroll
    for (int kt = 0; kt < 4; ++kt) {
      b8 fr = *(const b8*)(Wru + (size_t)(14+kt)*FRAG);
      b8 fz = *(const b8*)(Wzu + (size_t)(14+kt)*FRAG);
      b8 fn = *(const b8*)(Wnu + (size_t)(14+kt)*FRAG);
#pragma unroll
      for (int m = 0; m < 4; ++m) {
        b8 h = FR(s.OU, kt, m);
        aru[m] = MFMA16(h, fr, aru[m]);
        azu[m] = MFMA16(h, fz, azu[m]);
        ah[m]  = MFMA16(h, fn, ah[m]);
      }
    }
#pragma unroll
    for (int m = 0; m < 4; ++m)
#pragma unroll
      for (int r4 = 0; r4 < 4; ++r4) {
        const int row = m*16 + (l >> 4)*4 + r4;
        const float rr = sigmoid_(aru[m][r4]);
        const float zz = sigmoid_(azu[m][r4]);
        const float nn = tanh_(anu[m][r4] + rr*ah[m][r4]);
        const float h  = frag_elem(s.OU, row, col);
        s.HU[row][SWZ(row, col)] = f2bf((1.0f - zz)*nn + zz*h);
      }
  }

  // ---- item gh + ew -> h'_i into HI ----
  {
    f4 ah[4];
#pragma unroll
    for (int m = 0; m < 4; ++m) ah[m] = (f4){bhi,bhi,bhi,bhi};
#pragma unroll
    for (int kt = 0; kt < 4; ++kt) {
      b8 fr = *(const b8*)(Wri + (size_t)(14+kt)*FRAG);
      b8 fz = *(const b8*)(Wzi + (size_t)(14+kt)*FRAG);
      b8 fn = *(const b8*)(Wni + (size_t)(14+kt)*FRAG);
#pragma unroll
      for (int m = 0; m < 4; ++m) {
        b8 h = FR(s.OI, kt, m);
        ari[m] = MFMA16(h, fr, ari[m]);
        azi[m] = MFMA16(h, fz, azi[m]);
        ah[m]  = MFMA16(h, fn, ah[m]);
      }
    }
#pragma unroll
    for (int m = 0; m < 4; ++m)
#pragma unroll
      for (int r4 = 0; r4 < 4; ++r4) {
        const int row = m*16 + (l >> 4)*4 + r4;
        const float rr = sigmoid_(ari[m][r4]);
        const float zz = sigmoid_(azi[m][r4]);
        const float nn = tanh_(ani[m][r4] + rr*ah[m][r4]);
        const float h  = frag_elem(s.OI, row, col);
        s.HI[row][SWZ(row, col)] = f2bf((1.0f - zz)*nn + zz*h);
      }
  }
  __syncthreads();   // B2: HU + HI visible to all waves

  // ---- memory gates: shared gate_w fragments, user+item A streams ----
  {
    const float gb = gate_b[col];
    const ushort_t* WG = ws + PG_OFF + (size_t)wv*8*FRAG + l*8;
    f4 agu[4], agi[4];
#pragma unroll
    for (int m = 0; m < 4; ++m) { agu[m] = (f4){gb,gb,gb,gb}; agi[m] = agu[m]; }
#pragma unroll
    for (int kt = 0; kt < 8; ++kt) {
      b8 fg = *(const b8*)(WG + (size_t)kt*FRAG);
#pragma unroll
      for (int m = 0; m < 4; ++m) {
        b8 au = (kt < 4) ? FR(s.OU, kt, m)
                         : AFRAG(s.HU, m*16 + lrow, 32*(kt-4) + lk);
        b8 ai = (kt < 4) ? FR(s.OI, kt, m)
                         : AFRAG(s.HI, m*16 + lrow, 32*(kt-4) + lk);
        agu[m] = MFMA16(au, fg, agu[m]);
        agi[m] = MFMA16(ai, fg, agi[m]);
      }
    }
    float* __restrict__ outu = d_out + (size_t)CB*CE;
    float* __restrict__ outi = d_out + (size_t)2*CB*CE;
#pragma unroll
    for (int m = 0; m < 4; ++m)
#pragma unroll
      for (int r4 = 0; r4 < 4; ++r4) {
        const int row = m*16 + (l >> 4)*4 + r4;
        const float gu = sigmoid_(agu[m][r4]);
        const float gi = sigmoid_(agi[m][r4]);
        const float hu  = frag_elem(s.OU, row, col);
        const float hpu = bf2f(s.HU[row][SWZ(row, col)]);
        const float hi  = frag_elem(s.OI, row, col);
        const float hpi = bf2f(s.HI[row][SWZ(row, col)]);
        NTS(gu*hpu + (1.0f - gu)*hu, &outu[(size_t)(e0 + row)*CE + col]);
        NTS(gi*hpi + (1.0f - gi)*hi, &outi[(size_t)(e0 + row)*CE + col]);
      }
  }
}

extern "C" void kernel_launch(void* const* d_in, const int* in_sizes, int n_in,
                              void* d_out, int out_size, void* d_ws, size_t ws_size,
                              hipStream_t stream) {
  const int*   user_ids   = (const int*)d_in[0];
  const int*   item_ids   = (const int*)d_in[1];
  const float* timestamps = (const float*)d_in[2];
  const float* features   = (const float*)d_in[3];
  const int*   query_time = (const int*)d_in[4];
  const float* memv       = (const float*)d_in[5];
  const float* last_time  = (const float*)d_in[6];
  const float* time_w     = (const float*)d_in[7];
  const float* u_wih = (const float*)d_in[8];
  const float* u_whh = (const float*)d_in[9];
  const float* u_bih = (const float*)d_in[10];
  const float* u_bhh = (const float*)d_in[11];
  const float* i_wih = (const float*)d_in[12];
  const float* i_whh = (const float*)d_in[13];
  const float* i_bih = (const float*)d_in[14];
  const float* i_bhh = (const float*)d_in[15];
  const float* gate_w = (const float*)d_in[16];
  const float* gate_b = (const float*)d_in[17];
  const float* pred_w = (const float*)d_in[18];
  const float* pred_b = (const float*)d_in[19];
  ushort_t* ws = (ushort_t*)d_ws;
  float* out = (float*)d_out;

  prep_weights<<<dim3(256), dim3(256), 0, stream>>>(u_wih, u_whh, i_wih, i_whh,
                                                    gate_w, pred_w, ws);
  stage_gather<<<dim3(CB/32), dim3(512), 0, stream>>>(user_ids, item_ids, timestamps,
                                                      features, query_time, memv,
                                                      last_time, time_w, (char*)out);
  jodie_main<<<dim3(CB/EV), dim3(512), 0, stream>>>(time_w,
                                                    u_bih, u_bhh, i_bih, i_bhh,
                                                    gate_b, pred_b, ws, out);
}